// Round 10
// baseline (124.432 us; speedup 1.0000x reference)
//
#include <hip/hip_runtime.h>
#include <stdint.h>

typedef unsigned long long u64;

#define NMS_T 0.7f
#define MINSZ 16.0f
#define NPRE 6000
#define NPOST 300
#define CA   512
#define CAPA 2048
#define CAP6 8192
#define NBIN 2048
#define NSLOT 32

// ---- workspace layout (bytes) ----
#define OFF_CAND6  0                          // CAP6*8  = 65536
#define OFF_CANDA  (OFF_CAND6 + CAP6*8)       // CAPA*8  = 16384
#define OFF_ROIA   (OFF_CANDA + CAPA*8)       // CA*16   = 8192
#define OFF_VSUP   (OFF_ROIA + CA*16)         // 64  (VALID-bit mask, 8 u64)
#define OFF_ORDER6 (OFF_VSUP + 64)            // NPRE*4  (fallback)
#define OFF_ROI6   (OFF_ORDER6 + NPRE*4)      // NPRE*16 (fallback)
#define OFF_GMAT   (OFF_ROI6 + NPRE*16)       // CA*8*8 word-major gmat[w*CA+row]
#define OFF_SLOT   (OFF_GMAT + CA*64)         // NSLOT*NBIN*4
#define OFF_CNT    (OFF_SLOT + NSLOT*NBIN*4)  // 32: [0]=cntA [1]=cnt6

__device__ __forceinline__ unsigned inv_key(float s) {
    unsigned u = __float_as_uint(s);
    unsigned k = (u & 0x80000000u) ? ~u : (u | 0x80000000u);
    return ~k;   // ascending inv == descending score
}

__device__ __forceinline__ float4 decode_box(const float4 a, const float4 l,
                                             float ih, float iw) {
    float h  = a.z - a.x;
    float w  = a.w - a.y;
    float cy = a.x + 0.5f * h;
    float cx = a.y + 0.5f * w;
    float ncy = l.x * h + cy;
    float ncx = l.y * w + cx;
    float nh  = expf(l.z) * h;
    float nw  = expf(l.w) * w;
    float y1 = fminf(fmaxf(ncy - 0.5f * nh, 0.0f), ih);
    float x1 = fminf(fmaxf(ncx - 0.5f * nw, 0.0f), iw);
    float y2 = fminf(fmaxf(ncy + 0.5f * nh, 0.0f), ih);
    float x2 = fminf(fmaxf(ncx + 0.5f * nw, 0.0f), iw);
    return make_float4(y1, x1, y2, x2);
}

__device__ __forceinline__ int sbin_of(float s) {
    int b = (int)(s * 2048.0f);
    b = b < 0 ? 0 : (b > 2047 ? 2047 : b);
    return 2047 - b;           // ascending = descending score
}

__device__ __forceinline__ u64 readlane64(u64 v, int lane) {
    unsigned lo = (unsigned)__builtin_amdgcn_readlane((int)(unsigned)v, lane);
    unsigned hi = (unsigned)__builtin_amdgcn_readlane((int)(unsigned)(v >> 32), lane);
    return ((u64)hi << 32) | (u64)lo;
}

// block-wide (256 threads) scan of 2048-bin histogram; bins containing ranks t0/t1
__device__ void scan2048(const unsigned* __restrict__ h, unsigned t0, unsigned t1,
                         unsigned* psum, unsigned* res, int base) {
    int t = threadIdx.x;
    unsigned vals[8];
    unsigned s = 0;
#pragma unroll
    for (int j = 0; j < 8; j++) { vals[j] = h[t * 8 + j]; s += vals[j]; }
    psum[t] = s;
    __syncthreads();
    for (int off = 1; off < 256; off <<= 1) {
        unsigned v = (t >= off) ? psum[t - off] : 0u;
        __syncthreads();
        psum[t] += v;
        __syncthreads();
    }
    unsigned run = (t == 0) ? 0u : psum[t - 1];
#pragma unroll
    for (int j = 0; j < 8; j++) {
        unsigned c = vals[j];
        if (run < t0 && run + c >= t0) { res[base + 0] = t * 8 + j; res[base + 1] = run; }
        if (t1 && run < t1 && run + c >= t1) { res[base + 2] = t * 8 + j; res[base + 3] = run; }
        run += c;
    }
    __syncthreads();
}

// ---- 1: score-only histogram; 8x float4 register-batched loads ----
__global__ void __launch_bounds__(256) k_hist(const float* __restrict__ score, int n,
                                              unsigned* __restrict__ slots,
                                              unsigned* __restrict__ cnts) {
    __shared__ unsigned lh[NBIN];
    for (int b = threadIdx.x; b < NBIN; b += 256) lh[b] = 0;
    if (blockIdx.x == 0 && threadIdx.x < 8) cnts[threadIdx.x] = 0;
    __syncthreads();
    int gtid = blockIdx.x * 256 + threadIdx.x;
    int T = gridDim.x * 256;
    int n4 = n >> 2;
    const float4* s4 = (const float4*)score;
    for (int idx0 = gtid; idx0 < n4; idx0 += T * 8) {
        float4 v[8]; int ok[8];
#pragma unroll
        for (int k = 0; k < 8; ++k) {
            int idx = idx0 + k * T;
            ok[k] = idx < n4;
            v[k] = ok[k] ? s4[idx] : make_float4(0.f, 0.f, 0.f, 0.f);
        }
#pragma unroll
        for (int k = 0; k < 8; ++k) if (ok[k]) {
            atomicAdd(&lh[sbin_of(v[k].x)], 1u);
            atomicAdd(&lh[sbin_of(v[k].y)], 1u);
            atomicAdd(&lh[sbin_of(v[k].z)], 1u);
            atomicAdd(&lh[sbin_of(v[k].w)], 1u);
        }
    }
    for (int i = (n4 << 2) + gtid; i < n; i += T) atomicAdd(&lh[sbin_of(score[i])], 1u);
    __syncthreads();
    for (int b = threadIdx.x; b < NBIN; b += 256)
        slots[blockIdx.x * NBIN + b] = lh[b];
}

// ---- 2: thresholds -> mask-count -> block prefix -> winner decode+write ----
__global__ void __launch_bounds__(256) k_compact(
        const float4* __restrict__ loc, const float* __restrict__ score,
        const float4* __restrict__ anchor, const int* __restrict__ ph,
        const int* __restrict__ pw, int n, const unsigned* __restrict__ slots,
        u64* __restrict__ candA, u64* __restrict__ cand6, unsigned* __restrict__ cnts) {
    __shared__ unsigned hsum[NBIN];
    __shared__ unsigned psum[256];
    __shared__ unsigned res[8];
    __shared__ unsigned sbase[2];
    int tid = threadIdx.x;
    for (int b = tid; b < NBIN; b += 256) {
        unsigned s = 0;
#pragma unroll 4
        for (int sl = 0; sl < NSLOT; ++sl) s += slots[sl * NBIN + b];
        hsum[b] = s;
    }
    __syncthreads();
    scan2048(hsum, CA, NPRE, psum, res, 0);   // res0 = bA, res2 = b6
    unsigned bA = res[0], b6 = res[2];
    float ih = (float)ph[0], iw = (float)pw[0];
    int gtid = blockIdx.x * 256 + tid;
    int T = gridDim.x * 256;
    int n4 = n >> 2;
    const float4* s4 = (const float4*)score;
    // phase 1: count (8x float4 batched)
    unsigned c6 = 0, cA = 0;
    for (int idx0 = gtid; idx0 < n4; idx0 += T * 8) {
        float4 v[8]; int ok[8];
#pragma unroll
        for (int k = 0; k < 8; ++k) {
            int idx = idx0 + k * T;
            ok[k] = idx < n4;
            v[k] = ok[k] ? s4[idx] : make_float4(0.f, 0.f, 0.f, 0.f);
        }
#pragma unroll
        for (int k = 0; k < 8; ++k) if (ok[k]) {
            unsigned h0 = (unsigned)sbin_of(v[k].x), h1 = (unsigned)sbin_of(v[k].y);
            unsigned h2 = (unsigned)sbin_of(v[k].z), h3 = (unsigned)sbin_of(v[k].w);
            c6 += (h0 <= b6) + (h1 <= b6) + (h2 <= b6) + (h3 <= b6);
            cA += (h0 <= bA) + (h1 <= bA) + (h2 <= bA) + (h3 <= bA);
        }
    }
    int ntail = n4 << 2;
    for (int i = ntail + gtid; i < n; i += T) {
        unsigned hb = (unsigned)sbin_of(score[i]);
        c6 += (hb <= b6);
        cA += (hb <= bA);
    }
    psum[tid] = (cA << 16) | c6;
    __syncthreads();
    for (int off = 1; off < 256; off <<= 1) {
        unsigned v = (tid >= off) ? psum[tid - off] : 0u;
        __syncthreads();
        psum[tid] += v;
        __syncthreads();
    }
    if (tid == 0) {
        unsigned tot = psum[255];
        sbase[0] = atomicAdd(&cnts[1], tot & 0xFFFFu);
        sbase[1] = atomicAdd(&cnts[0], tot >> 16);
    }
    __syncthreads();
    unsigned excl = (tid == 0) ? 0u : psum[tid - 1];
    unsigned pos6 = sbase[0] + (excl & 0xFFFFu);
    unsigned posA = sbase[1] + (excl >> 16);
    // phase 2: reload (L2-hot), decode winners (~6.5K total), write keys
    for (int idx0 = gtid; idx0 < n4; idx0 += T * 8) {
        float4 v[8]; int ok[8];
#pragma unroll
        for (int k = 0; k < 8; ++k) {
            int idx = idx0 + k * T;
            ok[k] = idx < n4;
            v[k] = ok[k] ? s4[idx] : make_float4(0.f, 0.f, 0.f, 0.f);
        }
#pragma unroll
        for (int k = 0; k < 8; ++k) if (ok[k]) {
            float sc[4] = {v[k].x, v[k].y, v[k].z, v[k].w};
            int ib = (idx0 + k * T) << 2;
#pragma unroll
            for (int c = 0; c < 4; ++c) {
                unsigned hb = (unsigned)sbin_of(sc[c]);
                if (hb <= b6) {
                    int i = ib + c;
                    float4 r = decode_box(anchor[i], loc[i], ih, iw);
                    bool valid = ((r.z - r.x) >= MINSZ) && ((r.w - r.y) >= MINSZ);
                    float ms = valid ? sc[c] : -__builtin_inff();
                    u64 key = ((u64)inv_key(ms) << 32) | (unsigned)i;
                    if (pos6 < CAP6) cand6[pos6] = key;
                    pos6++;
                    if (hb <= bA) {
                        if (posA < CAPA) candA[posA] = key;
                        posA++;
                    }
                }
            }
        }
    }
    for (int i = ntail + gtid; i < n; i += T) {
        float s = score[i];
        unsigned hb = (unsigned)sbin_of(s);
        if (hb <= b6) {
            float4 r = decode_box(anchor[i], loc[i], ih, iw);
            bool valid = ((r.z - r.x) >= MINSZ) && ((r.w - r.y) >= MINSZ);
            float ms = valid ? s : -__builtin_inff();
            u64 key = ((u64)inv_key(ms) << 32) | (unsigned)i;
            if (pos6 < CAP6) cand6[pos6] = key;
            pos6++;
            if (hb <= bA) {
                if (posA < CAPA) candA[posA] = key;
                posA++;
            }
        }
    }
}

// register-blocked exact rank + decode of top-CA; j-loop batched 16-wide to break
// the per-iteration LDS latency chain (broadcast reads, independent)
template <int KB>
__device__ __forceinline__ void rank_block(const u64* lk, unsigned MP,
                                           const float4* anchor, const float4* loc,
                                           float ih, float iw,
                                           float4* sroi, float* sarea, unsigned* svalid) {
    u64 kc[KB]; int rr[KB];
#pragma unroll
    for (int k = 0; k < KB; ++k) {
        unsigned c = threadIdx.x + k * 256u;
        kc[k] = (c < MP) ? lk[c] : ~0ULL;
        rr[k] = 0;
    }
    unsigned j = 0;
    for (; j + 16 <= MP; j += 16) {
        u64 kj[16];
#pragma unroll
        for (int t = 0; t < 16; ++t) kj[t] = lk[j + t];
#pragma unroll
        for (int t = 0; t < 16; ++t) {
#pragma unroll
            for (int k = 0; k < KB; ++k) rr[k] += (kj[t] < kc[k]) ? 1 : 0;
        }
    }
    for (; j < MP; ++j) {
        u64 kj = lk[j];
#pragma unroll
        for (int k = 0; k < KB; ++k) rr[k] += (kj < kc[k]) ? 1 : 0;
    }
#pragma unroll
    for (int k = 0; k < KB; ++k) {
        unsigned c = threadIdx.x + k * 256u;
        if (c < MP && rr[k] < CA) {
            unsigned idx = (unsigned)kc[k];
            float4 b = decode_box(anchor[idx], loc[idx], ih, iw);
            sroi[rr[k]] = b;
            sarea[rr[k]] = (b.z - b.x) * (b.w - b.y);
            if (((b.z - b.x) >= MINSZ) && ((b.w - b.y) >= MINSZ))
                atomicOr(&svalid[rr[k] >> 5], 1u << (rr[k] & 31));
        }
    }
}

// ---- 3: 8 parallel blocks: direct rank of all candA -> decode -> matrix slice ----
// (no prune pipeline: ranks vs full candA ARE the global ranks; CAPA bounds work)
__global__ void __launch_bounds__(256) k_rankmat(
        const float4* __restrict__ loc, const float4* __restrict__ anchor,
        const int* __restrict__ ph, const int* __restrict__ pw,
        const u64* __restrict__ candA, const unsigned* __restrict__ cnts,
        u64* __restrict__ gmat, float4* __restrict__ roiA, u64* __restrict__ vsup_g) {
    __shared__ u64 lk[CAPA];
    __shared__ float4 sroi[CA];
    __shared__ float sarea[CA];
    __shared__ unsigned svalid[CA / 32];
    int tid = threadIdx.x;
    unsigned cntA = cnts[0];
    if (cntA > CAPA) return;                      // flag path handled in k_scan
    unsigned MA = cntA;
    float ih = (float)ph[0], iw = (float)pw[0];

    for (int r = tid; r < CA; r += 256) { sroi[r] = make_float4(0.f,0.f,0.f,0.f); sarea[r] = 0.f; }
    if (tid < CA / 32) svalid[tid] = 0;
    for (unsigned i = tid; i < MA; i += 256) lk[i] = candA[i];
    __syncthreads();
    if (MA <= 1024) rank_block<4>(lk, MA, anchor, loc, ih, iw, sroi, sarea, svalid);
    else            rank_block<8>(lk, MA, anchor, loc, ih, iw, sroi, sarea, svalid);
    __syncthreads();
    int w = blockIdx.x;
    int j0 = w * 64;
#pragma unroll
    for (int rrr = 0; rrr < 2; ++rrr) {
        int row = tid + rrr * 256;
        u64 bits = 0;
        if (j0 + 63 > row) {
            float4 b = sroi[row];
            float ab = sarea[row];
#pragma unroll 4
            for (int jj = 0; jj < 64; ++jj) {
                int j = j0 + jj;
                if (j > row) {
                    float4 c = sroi[j];
                    float yy1 = fmaxf(b.x, c.x);
                    float xx1 = fmaxf(b.y, c.y);
                    float yy2 = fminf(b.z, c.z);
                    float xx2 = fminf(b.w, c.w);
                    float inter = fmaxf(yy2 - yy1, 0.0f) * fmaxf(xx2 - xx1, 0.0f);
                    float iou = inter / (ab + sarea[j] - inter);  // ref op order
                    if (iou > NMS_T) bits |= (1ULL << jj);
                }
            }
        }
        gmat[w * CA + row] = bits;
    }
    if (blockIdx.x == 0) {
        for (int r = tid; r < CA; r += 256) roiA[r] = sroi[r];
        if (tid < 8) vsup_g[tid] = ((u64)svalid[2 * tid + 1] << 32) | (u64)svalid[2 * tid];
    }
}

struct SmFb {
    u64   lk[CAP6];                                // 64 KB
    float y1[NPOST], x1[NPOST], y2[NPOST], x2[NPOST], ar[NPOST];
};

// ---- 4: single block: group-serial scan, O(1) per kept + deferred butterfly fold ----
__global__ void __launch_bounds__(256) k_scan(
        const float4* __restrict__ loc, const float4* __restrict__ anchor,
        const int* __restrict__ ph, const int* __restrict__ pw, int n,
        const u64* __restrict__ cand6, const unsigned* __restrict__ cnts,
        const float4* __restrict__ roiA, const u64* __restrict__ vsup_g,
        const u64* __restrict__ gmat,
        unsigned* __restrict__ order6, float4* __restrict__ roi6,
        float* __restrict__ out) {
    __shared__ SmFb fb;
    __shared__ u64 skm[8];
    __shared__ int snk, sflag;
    int tid = threadIdx.x;
    unsigned cntA = cnts[0], cnt6 = cnts[1];
    bool mainValid = (cntA <= CAPA);
    int Ceff = (int)(cntA < (unsigned)CA ? cntA : (unsigned)CA);
    float ih = (float)ph[0], iw = (float)pw[0];

    if (tid < 64 && mainValid) {
        u64 supfut[8], curM[8], nxtM[8], kmask[8];
#pragma unroll
        for (int w = 0; w < 8; ++w) { supfut[w] = ~vsup_g[w]; kmask[w] = 0ull; }
#pragma unroll
        for (int w = 0; w < 8; ++w) curM[w] = gmat[w * CA + tid];
        int nk = 0;
        bool done = false;
#pragma unroll
        for (int g = 0; g < 8; ++g) {
            if (g < 7) {
#pragma unroll
                for (int w = 0; w < 8; ++w) nxtM[w] = gmat[w * CA + 64 * (g + 1) + tid];
            }
            int base = 64 * g;
            if (!done && base < Ceff) {
                u64 bound = (Ceff - base >= 64) ? ~0ull : ((1ull << (Ceff - base)) - 1ull);
                u64 live = ~supfut[g] & bound;
                u64 km = 0;
                while (live) {
                    int b = (int)__builtin_ctzll(live);
                    km |= (1ull << b);
                    ++nk;
                    if (nk == NPOST) { done = true; break; }
                    u64 row = readlane64(curM[g], b);   // word g of kept row: 2 readlanes
                    live &= ~(row | (1ull << b));
                }
                kmask[g] = km;
                if (!done && g < 7) {                   // deferred cross-group fold
                    bool mk = ((km >> tid) & 1ull) != 0ull;
                    u64 c[8];
#pragma unroll
                    for (int w = g + 1; w < 8; ++w) c[w] = mk ? curM[w] : 0ull;
#pragma unroll
                    for (int off = 1; off < 64; off <<= 1) {
#pragma unroll
                        for (int w = g + 1; w < 8; ++w) c[w] |= __shfl_xor(c[w], off, 64);
                    }
#pragma unroll
                    for (int w = g + 1; w < 8; ++w) supfut[w] |= c[w];
                }
            }
#pragma unroll
            for (int w = 0; w < 8; ++w) curM[w] = nxtM[w];
        }
        if (tid == 0) {
            snk = nk;
            sflag = (nk < NPOST && cnt6 > (unsigned)Ceff) ? 1 : 0;
            skm[0] = kmask[0]; skm[1] = kmask[1]; skm[2] = kmask[2]; skm[3] = kmask[3];
            skm[4] = kmask[4]; skm[5] = kmask[5]; skm[6] = kmask[6]; skm[7] = kmask[7];
        }
    }
    if (tid == 0 && !mainValid) {
        snk = 0; sflag = 1;
        skm[0]=0; skm[1]=0; skm[2]=0; skm[3]=0; skm[4]=0; skm[5]=0; skm[6]=0; skm[7]=0;
    }
    __syncthreads();
    int nk = snk, flag = sflag;
    float4* out4 = (float4*)out;
    if (!flag) {
        int basepc[8];
        {
            int run = 0;
#pragma unroll
            for (int g = 0; g < 8; ++g) { basepc[g] = run; run += __popcll(skm[g]); }
        }
        int wv = tid >> 6, j = tid & 63;
#pragma unroll
        for (int gg = 0; gg < 2; ++gg) {
            int g = wv * 2 + gg;
            u64 km = skm[g];
            if ((km >> j) & 1ull) {
                int rank = basepc[g] + __popcll(km & ((1ull << j) - 1ull));
                if (rank < NPOST) out4[rank] = roiA[64 * g + j];
            }
        }
        for (int k = nk + tid; k < NPOST; k += 256) out4[k] = make_float4(0.f,0.f,0.f,0.f);
        return;
    }
    // ---------- exact fallback (gated; never taken on sane data) ----------
    unsigned M = cnt6 < (unsigned)CAP6 ? cnt6 : (unsigned)CAP6;
    for (unsigned i = tid; i < CAP6; i += 256) fb.lk[i] = (i < M) ? cand6[i] : ~0ULL;
    for (int r = tid; r < NPRE; r += 256) order6[r] = 0xFFFFFFFFu;
    __syncthreads();
    for (unsigned c = tid; c < M; c += 256) {
        u64 key = fb.lk[c];
        int rank = 0;
        for (unsigned j = 0; j < M; ++j) rank += (fb.lk[j] < key) ? 1 : 0;
        if (rank < NPRE) order6[rank] = (unsigned)key;
    }
    __syncthreads();
    for (int r = tid; r < NPRE; r += 256) {
        unsigned idx = order6[r];
        float4 b = make_float4(0.f, 0.f, 0.f, 0.f);
        if (idx < (unsigned)n) b = decode_box(anchor[idx], loc[idx], ih, iw);
        roi6[r] = b;
    }
    __syncthreads();
    if (tid < 64) {
        int lane = tid;
        int nk2 = 0;
        for (int i = 0; i < NPRE; i++) {
            float4 b = roi6[i];
            float hs = b.z - b.x, wd = b.w - b.y;
            if (!(hs >= MINSZ && wd >= MINSZ)) continue;
            float ab = hs * wd;
            bool sup = false;
            for (int base = 0; base < nk2 && !sup; base += 64) {
                int t = base + lane;
                bool s = false;
                if (t < nk2) {
                    float yy1 = fmaxf(b.x, fb.y1[t]);
                    float xx1 = fmaxf(b.y, fb.x1[t]);
                    float yy2 = fminf(b.z, fb.y2[t]);
                    float xx2 = fminf(b.w, fb.x2[t]);
                    float inter = fmaxf(yy2 - yy1, 0.0f) * fmaxf(xx2 - xx1, 0.0f);
                    float iou = inter / (fb.ar[t] + ab - inter);
                    s = iou > NMS_T;
                }
                sup = (__ballot(s) != 0ULL);
            }
            if (!sup) {
                if (lane == 0) {
                    fb.y1[nk2] = b.x; fb.x1[nk2] = b.y;
                    fb.y2[nk2] = b.z; fb.x2[nk2] = b.w; fb.ar[nk2] = ab;
                }
                nk2++;
                if (nk2 == NPOST) break;
            }
        }
        for (int k = lane; k < NPOST; k += 64) {
            float4 o = make_float4(0.f, 0.f, 0.f, 0.f);
            if (k < nk2) o = make_float4(fb.y1[k], fb.x1[k], fb.y2[k], fb.x2[k]);
            out4[k] = o;
        }
    }
}

extern "C" void kernel_launch(void* const* d_in, const int* in_sizes, int n_in,
                              void* d_out, int out_size, void* d_ws, size_t ws_size,
                              hipStream_t stream) {
    const float4* loc    = (const float4*)d_in[0];
    const float*  score  = (const float*)d_in[1];
    const float4* anchor = (const float4*)d_in[2];
    const int*    ph     = (const int*)d_in[3];
    const int*    pw     = (const int*)d_in[4];
    int n = in_sizes[1];

    char* ws = (char*)d_ws;
    u64*      cand6  = (u64*)(ws + OFF_CAND6);
    u64*      candA  = (u64*)(ws + OFF_CANDA);
    float4*   roiA   = (float4*)(ws + OFF_ROIA);
    u64*      vsup   = (u64*)(ws + OFF_VSUP);
    unsigned* order6 = (unsigned*)(ws + OFF_ORDER6);
    float4*   roi6   = (float4*)(ws + OFF_ROI6);
    u64*      gmat   = (u64*)(ws + OFF_GMAT);
    unsigned* slots  = (unsigned*)(ws + OFF_SLOT);
    unsigned* cnts   = (unsigned*)(ws + OFF_CNT);
    float* out = (float*)d_out;

    k_hist    <<<dim3(NSLOT), dim3(256), 0, stream>>>(score, n, slots, cnts);
    k_compact <<<dim3(128),   dim3(256), 0, stream>>>(loc, score, anchor, ph, pw, n, slots,
                                                      candA, cand6, cnts);
    k_rankmat <<<dim3(8),     dim3(256), 0, stream>>>(loc, anchor, ph, pw, candA, cnts,
                                                      gmat, roiA, vsup);
    k_scan    <<<dim3(1),     dim3(256), 0, stream>>>(loc, anchor, ph, pw, n, cand6, cnts,
                                                      roiA, vsup, gmat, order6, roi6, out);
}

// Round 11
// 94.329 us; speedup vs baseline: 1.3191x; 1.3191x over previous
//
#include <hip/hip_runtime.h>
#include <stdint.h>

typedef unsigned long long u64;

#define NMS_T 0.7f
#define MINSZ 16.0f
#define NPRE 6000
#define NPOST 300
#define CA   512
#define CAPA 2048
#define CAP6 8192
#define NBIN 2048
#define NSLOT 32
#define GRIDR 16

// ---- workspace layout (bytes) ----
#define OFF_CAND6  0                          // CAP6*8  = 65536
#define OFF_CANDA  (OFF_CAND6 + CAP6*8)       // CAPA*8  = 16384
#define OFF_ROIA   (OFF_CANDA + CAPA*8)       // CA*16   = 8192
#define OFF_VSUP   (OFF_ROIA + CA*16)         // 64  (VALID-bit mask, 8 u64)
#define OFF_ORDER6 (OFF_VSUP + 64)            // NPRE*4  (fallback)
#define OFF_ROI6   (OFF_ORDER6 + NPRE*4)      // NPRE*16 (fallback)
#define OFF_GMAT   (OFF_ROI6 + NPRE*16)       // CA*8*8 word-major gmat[w*CA+row]
#define OFF_SLOT   (OFF_GMAT + CA*64)         // NSLOT*NBIN*4
#define OFF_CNT    (OFF_SLOT + NSLOT*NBIN*4)  // 32: [0]=cntA [1]=cnt6

__device__ __forceinline__ unsigned inv_key(float s) {
    unsigned u = __float_as_uint(s);
    unsigned k = (u & 0x80000000u) ? ~u : (u | 0x80000000u);
    return ~k;   // ascending inv == descending score
}

__device__ __forceinline__ float4 decode_box(const float4 a, const float4 l,
                                             float ih, float iw) {
    float h  = a.z - a.x;
    float w  = a.w - a.y;
    float cy = a.x + 0.5f * h;
    float cx = a.y + 0.5f * w;
    float ncy = l.x * h + cy;
    float ncx = l.y * w + cx;
    float nh  = expf(l.z) * h;
    float nw  = expf(l.w) * w;
    float y1 = fminf(fmaxf(ncy - 0.5f * nh, 0.0f), ih);
    float x1 = fminf(fmaxf(ncx - 0.5f * nw, 0.0f), iw);
    float y2 = fminf(fmaxf(ncy + 0.5f * nh, 0.0f), ih);
    float x2 = fminf(fmaxf(ncx + 0.5f * nw, 0.0f), iw);
    return make_float4(y1, x1, y2, x2);
}

__device__ __forceinline__ int sbin_of(float s) {
    int b = (int)(s * 2048.0f);
    b = b < 0 ? 0 : (b > 2047 ? 2047 : b);
    return 2047 - b;           // ascending = descending score
}

__device__ __forceinline__ u64 readlane64(u64 v, int lane) {
    unsigned lo = (unsigned)__builtin_amdgcn_readlane((int)(unsigned)v, lane);
    unsigned hi = (unsigned)__builtin_amdgcn_readlane((int)(unsigned)(v >> 32), lane);
    return ((u64)hi << 32) | (u64)lo;
}

// fast block scan of 2048-bin histogram (2 barriers): finds bins with ranks t0/t1
__device__ void fastscan2048(const unsigned* __restrict__ h, unsigned t0, unsigned t1,
                             unsigned* swave, unsigned* res) {
    int t = threadIdx.x;
    unsigned vals[8], s = 0;
#pragma unroll
    for (int j = 0; j < 8; ++j) { vals[j] = h[t * 8 + j]; s += vals[j]; }
    unsigned inc = s;
#pragma unroll
    for (int off = 1; off < 64; off <<= 1) {
        unsigned o = (unsigned)__shfl_up((int)inc, off, 64);
        if ((t & 63) >= off) inc += o;
    }
    if ((t & 63) == 63) swave[t >> 6] = inc;
    __syncthreads();
    unsigned wbase = 0;
    for (int w = 0; w < (t >> 6); ++w) wbase += swave[w];
    unsigned run = wbase + inc - s;
#pragma unroll
    for (int j = 0; j < 8; ++j) {
        unsigned c = vals[j];
        if (run < t0 && run + c >= t0) { res[0] = t * 8 + j; res[1] = run; }
        if (t1 && run < t1 && run + c >= t1) { res[2] = t * 8 + j; res[3] = run; }
        run += c;
    }
    __syncthreads();
}

// ---- 1: score-only histogram; 8x float4 register-batched loads ----
__global__ void __launch_bounds__(256) k_hist(const float* __restrict__ score, int n,
                                              unsigned* __restrict__ slots,
                                              unsigned* __restrict__ cnts) {
    __shared__ unsigned lh[NBIN];
    for (int b = threadIdx.x; b < NBIN; b += 256) lh[b] = 0;
    if (blockIdx.x == 0 && threadIdx.x < 8) cnts[threadIdx.x] = 0;
    __syncthreads();
    int gtid = blockIdx.x * 256 + threadIdx.x;
    int T = gridDim.x * 256;
    int n4 = n >> 2;
    const float4* s4 = (const float4*)score;
    for (int idx0 = gtid; idx0 < n4; idx0 += T * 8) {
        float4 v[8]; int ok[8];
#pragma unroll
        for (int k = 0; k < 8; ++k) {
            int idx = idx0 + k * T;
            ok[k] = idx < n4;
            v[k] = ok[k] ? s4[idx] : make_float4(0.f, 0.f, 0.f, 0.f);
        }
#pragma unroll
        for (int k = 0; k < 8; ++k) if (ok[k]) {
            atomicAdd(&lh[sbin_of(v[k].x)], 1u);
            atomicAdd(&lh[sbin_of(v[k].y)], 1u);
            atomicAdd(&lh[sbin_of(v[k].z)], 1u);
            atomicAdd(&lh[sbin_of(v[k].w)], 1u);
        }
    }
    for (int i = (n4 << 2) + gtid; i < n; i += T) atomicAdd(&lh[sbin_of(score[i])], 1u);
    __syncthreads();
    for (int b = threadIdx.x; b < NBIN; b += 256)
        slots[blockIdx.x * NBIN + b] = lh[b];
}

// ---- 2: thresholds -> mask-count -> block prefix -> winner decode+write ----
__global__ void __launch_bounds__(256) k_compact(
        const float4* __restrict__ loc, const float* __restrict__ score,
        const float4* __restrict__ anchor, const int* __restrict__ ph,
        const int* __restrict__ pw, int n, const unsigned* __restrict__ slots,
        u64* __restrict__ candA, u64* __restrict__ cand6, unsigned* __restrict__ cnts) {
    __shared__ unsigned hsum[NBIN];
    __shared__ unsigned psum[256];
    __shared__ unsigned res[8];
    __shared__ unsigned swave[8];
    __shared__ unsigned sbase[2];
    int tid = threadIdx.x;
    for (int b = tid; b < NBIN; b += 256) {
        unsigned s = 0;
#pragma unroll 4
        for (int sl = 0; sl < NSLOT; ++sl) s += slots[sl * NBIN + b];
        hsum[b] = s;
    }
    __syncthreads();
    fastscan2048(hsum, CA, NPRE, swave, res);   // res0 = bA, res2 = b6
    unsigned bA = res[0], b6 = res[2];
    float ih = (float)ph[0], iw = (float)pw[0];
    int gtid = blockIdx.x * 256 + tid;
    int T = gridDim.x * 256;
    int n4 = n >> 2;
    const float4* s4 = (const float4*)score;
    // phase 1: count (8x float4 batched)
    unsigned c6 = 0, cA = 0;
    for (int idx0 = gtid; idx0 < n4; idx0 += T * 8) {
        float4 v[8]; int ok[8];
#pragma unroll
        for (int k = 0; k < 8; ++k) {
            int idx = idx0 + k * T;
            ok[k] = idx < n4;
            v[k] = ok[k] ? s4[idx] : make_float4(0.f, 0.f, 0.f, 0.f);
        }
#pragma unroll
        for (int k = 0; k < 8; ++k) if (ok[k]) {
            unsigned h0 = (unsigned)sbin_of(v[k].x), h1 = (unsigned)sbin_of(v[k].y);
            unsigned h2 = (unsigned)sbin_of(v[k].z), h3 = (unsigned)sbin_of(v[k].w);
            c6 += (h0 <= b6) + (h1 <= b6) + (h2 <= b6) + (h3 <= b6);
            cA += (h0 <= bA) + (h1 <= bA) + (h2 <= bA) + (h3 <= bA);
        }
    }
    int ntail = n4 << 2;
    for (int i = ntail + gtid; i < n; i += T) {
        unsigned hb = (unsigned)sbin_of(score[i]);
        c6 += (hb <= b6);
        cA += (hb <= bA);
    }
    psum[tid] = (cA << 16) | c6;
    __syncthreads();
    for (int off = 1; off < 256; off <<= 1) {
        unsigned v = (tid >= off) ? psum[tid - off] : 0u;
        __syncthreads();
        psum[tid] += v;
        __syncthreads();
    }
    if (tid == 0) {
        unsigned tot = psum[255];
        sbase[0] = atomicAdd(&cnts[1], tot & 0xFFFFu);
        sbase[1] = atomicAdd(&cnts[0], tot >> 16);
    }
    __syncthreads();
    unsigned excl = (tid == 0) ? 0u : psum[tid - 1];
    unsigned pos6 = sbase[0] + (excl & 0xFFFFu);
    unsigned posA = sbase[1] + (excl >> 16);
    // phase 2: reload (L2-hot), decode winners (~6.5K total), write keys
    for (int idx0 = gtid; idx0 < n4; idx0 += T * 8) {
        float4 v[8]; int ok[8];
#pragma unroll
        for (int k = 0; k < 8; ++k) {
            int idx = idx0 + k * T;
            ok[k] = idx < n4;
            v[k] = ok[k] ? s4[idx] : make_float4(0.f, 0.f, 0.f, 0.f);
        }
#pragma unroll
        for (int k = 0; k < 8; ++k) if (ok[k]) {
            float sc[4] = {v[k].x, v[k].y, v[k].z, v[k].w};
            int ib = (idx0 + k * T) << 2;
#pragma unroll
            for (int c = 0; c < 4; ++c) {
                unsigned hb = (unsigned)sbin_of(sc[c]);
                if (hb <= b6) {
                    int i = ib + c;
                    float4 r = decode_box(anchor[i], loc[i], ih, iw);
                    bool valid = ((r.z - r.x) >= MINSZ) && ((r.w - r.y) >= MINSZ);
                    float ms = valid ? sc[c] : -__builtin_inff();
                    u64 key = ((u64)inv_key(ms) << 32) | (unsigned)i;
                    if (pos6 < CAP6) cand6[pos6] = key;
                    pos6++;
                    if (hb <= bA) {
                        if (posA < CAPA) candA[posA] = key;
                        posA++;
                    }
                }
            }
        }
    }
    for (int i = ntail + gtid; i < n; i += T) {
        float s = score[i];
        unsigned hb = (unsigned)sbin_of(s);
        if (hb <= b6) {
            float4 r = decode_box(anchor[i], loc[i], ih, iw);
            bool valid = ((r.z - r.x) >= MINSZ) && ((r.w - r.y) >= MINSZ);
            float ms = valid ? s : -__builtin_inff();
            u64 key = ((u64)inv_key(ms) << 32) | (unsigned)i;
            if (pos6 < CAP6) cand6[pos6] = key;
            pos6++;
            if (hb <= bA) {
                if (posA < CAPA) candA[posA] = key;
                posA++;
            }
        }
    }
}

// ---- 3: GRIDR blocks: O(M) counting-sort rank -> decode -> matrix slice ----
// rank = prefix[bucket] + exact within-bucket compare (bitwise-exact any data)
__global__ void __launch_bounds__(256) k_rankmat(
        const float4* __restrict__ loc, const float4* __restrict__ anchor,
        const int* __restrict__ ph, const int* __restrict__ pw,
        const u64* __restrict__ candA, const unsigned* __restrict__ cnts,
        u64* __restrict__ gmat, float4* __restrict__ roiA, u64* __restrict__ vsup_g) {
    __shared__ u64 skey[CAPA];          // 16 KB
    __shared__ unsigned shist[NBIN];    // 8 KB
    __shared__ unsigned sprefix[NBIN];  // 8 KB
    __shared__ float4 sroi[CA];         // 8 KB
    __shared__ float  sarea[CA];        // 2 KB
    __shared__ unsigned svalid[CA / 32];
    __shared__ unsigned swave[8];
    __shared__ unsigned sInvLo;
    int tid = threadIdx.x;
    unsigned cntA = cnts[0];
    if (cntA > CAPA) return;                      // flag path handled in k_scan
    unsigned MA = cntA;
    float ih = (float)ph[0], iw = (float)pw[0];

    if (tid == 0) sInvLo = 0xFFFFFFFFu;
    for (int b = tid; b < NBIN; b += 256) shist[b] = 0;
    for (int r = tid; r < CA; r += 256) { sroi[r] = make_float4(0.f,0.f,0.f,0.f); sarea[r] = 0.f; }
    if (tid < CA / 32) svalid[tid] = 0;
    // keys into registers (MA <= CAPA = 2048 = 8*256)
    u64 kreg[8];
#pragma unroll
    for (int k = 0; k < 8; ++k) {
        unsigned i = tid + k * 256u;
        kreg[k] = (i < MA) ? candA[i] : ~0ULL;
    }
    // wave-reduced min of inv (padded keys have inv=0xFFFFFFFF, harmless)
    unsigned mymin = 0xFFFFFFFFu;
#pragma unroll
    for (int k = 0; k < 8; ++k) {
        unsigned hi = (unsigned)(kreg[k] >> 32);
        mymin = mymin < hi ? mymin : hi;
    }
#pragma unroll
    for (int off = 32; off; off >>= 1) {
        unsigned o = (unsigned)__shfl_down((int)mymin, off, 64);
        mymin = mymin < o ? mymin : o;
    }
    if ((tid & 63) == 0) atomicMin(&sInvLo, mymin);
    __syncthreads();
    unsigned invLo = sInvLo;
    // histogram on bucket = clamp((inv - invLo) >> 3, 2047)
#pragma unroll
    for (int k = 0; k < 8; ++k) {
        unsigned i = tid + k * 256u;
        if (i < MA) {
            unsigned d = ((unsigned)(kreg[k] >> 32) - invLo) >> 3;
            atomicAdd(&shist[d > 2047u ? 2047u : d], 1u);
        }
    }
    __syncthreads();
    // fast exclusive prefix into sprefix (2 barriers via shfl scan)
    {
        unsigned vals[8], s = 0;
#pragma unroll
        for (int j = 0; j < 8; ++j) { vals[j] = shist[tid * 8 + j]; s += vals[j]; }
        unsigned inc = s;
#pragma unroll
        for (int off = 1; off < 64; off <<= 1) {
            unsigned o = (unsigned)__shfl_up((int)inc, off, 64);
            if ((tid & 63) >= off) inc += o;
        }
        if ((tid & 63) == 63) swave[tid >> 6] = inc;
        __syncthreads();
        unsigned wbase = 0;
        for (int w = 0; w < (tid >> 6); ++w) wbase += swave[w];
        unsigned run = wbase + inc - s;
#pragma unroll
        for (int j = 0; j < 8; ++j) { sprefix[tid * 8 + j] = run; run += vals[j]; }
    }
    __syncthreads();
    // scatter (atomicAdd on sprefix gives arbitrary within-bucket order; fixed below)
#pragma unroll
    for (int k = 0; k < 8; ++k) {
        unsigned i = tid + k * 256u;
        if (i < MA) {
            unsigned d = ((unsigned)(kreg[k] >> 32) - invLo) >> 3;
            d = d > 2047u ? 2047u : d;
            unsigned pos = atomicAdd(&sprefix[d], 1u);
            skey[pos] = kreg[k];
        }
    }
    __syncthreads();
    // exact rank fixup (segment [e-cnt, e), tiny) + decode into sroi[rank]
#pragma unroll
    for (int k = 0; k < 8; ++k) {
        unsigned p = tid + k * 256u;
        if (p < MA) {
            u64 key = skey[p];
            unsigned d = ((unsigned)(key >> 32) - invLo) >> 3;
            d = d > 2047u ? 2047u : d;
            unsigned e = sprefix[d];            // post-scatter = segment end
            unsigned s0 = e - shist[d];
            int rank = (int)s0;
            for (unsigned q = s0; q < e; ++q) rank += (skey[q] < key) ? 1 : 0;
            if (rank < CA) {
                unsigned idx = (unsigned)key;
                float4 b = decode_box(anchor[idx], loc[idx], ih, iw);
                sroi[rank] = b;
                sarea[rank] = (b.z - b.x) * (b.w - b.y);
                if (((b.z - b.x) >= MINSZ) && ((b.w - b.y) >= MINSZ))
                    atomicOr(&svalid[rank >> 5], 1u << (rank & 31));
            }
        }
    }
    __syncthreads();
    // matrix slice: word w = bid>>1, row = (bid&1)*256 + tid (1 row-word/thread)
    {
        int w = blockIdx.x >> 1;
        int row = ((blockIdx.x & 1) << 8) + tid;
        u64 bits = 0;
        int j0 = w << 6;
        if (j0 + 63 > row) {
            float4 b = sroi[row];
            float ab = sarea[row];
#pragma unroll 4
            for (int jj = 0; jj < 64; ++jj) {
                int j = j0 + jj;
                if (j > row) {
                    float4 c = sroi[j];
                    float yy1 = fmaxf(b.x, c.x);
                    float xx1 = fmaxf(b.y, c.y);
                    float yy2 = fminf(b.z, c.z);
                    float xx2 = fminf(b.w, c.w);
                    float inter = fmaxf(yy2 - yy1, 0.0f) * fmaxf(xx2 - xx1, 0.0f);
                    float iou = inter / (ab + sarea[j] - inter);  // ref op order
                    if (iou > NMS_T) bits |= (1ULL << jj);
                }
            }
        }
        gmat[w * CA + row] = bits;
    }
    if (blockIdx.x == 0) {
        for (int r = tid; r < CA; r += 256) roiA[r] = sroi[r];
        if (tid < 8) vsup_g[tid] = ((u64)svalid[2 * tid + 1] << 32) | (u64)svalid[2 * tid];
    }
}

struct SmFb {
    u64   lk[CAP6];                                // 64 KB
    float y1[NPOST], x1[NPOST], y2[NPOST], x2[NPOST], ar[NPOST];
};

// ---- 4: single block: group-serial scan, O(1) per kept + deferred butterfly fold ----
__global__ void __launch_bounds__(256) k_scan(
        const float4* __restrict__ loc, const float4* __restrict__ anchor,
        const int* __restrict__ ph, const int* __restrict__ pw, int n,
        const u64* __restrict__ cand6, const unsigned* __restrict__ cnts,
        const float4* __restrict__ roiA, const u64* __restrict__ vsup_g,
        const u64* __restrict__ gmat,
        unsigned* __restrict__ order6, float4* __restrict__ roi6,
        float* __restrict__ out) {
    __shared__ SmFb fb;
    __shared__ u64 skm[8];
    __shared__ int snk, sflag;
    int tid = threadIdx.x;
    unsigned cntA = cnts[0], cnt6 = cnts[1];
    bool mainValid = (cntA <= CAPA);
    int Ceff = (int)(cntA < (unsigned)CA ? cntA : (unsigned)CA);
    float ih = (float)ph[0], iw = (float)pw[0];

    if (tid < 64 && mainValid) {
        u64 supfut[8], curM[8], nxtM[8], kmask[8];
#pragma unroll
        for (int w = 0; w < 8; ++w) { supfut[w] = ~vsup_g[w]; kmask[w] = 0ull; }
#pragma unroll
        for (int w = 0; w < 8; ++w) curM[w] = gmat[w * CA + tid];
        int nk = 0;
        bool done = false;
#pragma unroll
        for (int g = 0; g < 8; ++g) {
            if (g < 7) {
#pragma unroll
                for (int w = 0; w < 8; ++w) nxtM[w] = gmat[w * CA + 64 * (g + 1) + tid];
            }
            int base = 64 * g;
            if (!done && base < Ceff) {
                u64 bound = (Ceff - base >= 64) ? ~0ull : ((1ull << (Ceff - base)) - 1ull);
                u64 live = ~supfut[g] & bound;
                u64 km = 0;
                while (live) {
                    int b = (int)__builtin_ctzll(live);
                    km |= (1ull << b);
                    ++nk;
                    if (nk == NPOST) { done = true; break; }
                    u64 row = readlane64(curM[g], b);   // word g of kept row: 2 readlanes
                    live &= ~(row | (1ull << b));
                }
                kmask[g] = km;
                if (!done && g < 7) {                   // deferred cross-group fold
                    bool mk = ((km >> tid) & 1ull) != 0ull;
                    u64 c[8];
#pragma unroll
                    for (int w = g + 1; w < 8; ++w) c[w] = mk ? curM[w] : 0ull;
#pragma unroll
                    for (int off = 1; off < 64; off <<= 1) {
#pragma unroll
                        for (int w = g + 1; w < 8; ++w) c[w] |= __shfl_xor(c[w], off, 64);
                    }
#pragma unroll
                    for (int w = g + 1; w < 8; ++w) supfut[w] |= c[w];
                }
            }
#pragma unroll
            for (int w = 0; w < 8; ++w) curM[w] = nxtM[w];
        }
        if (tid == 0) {
            snk = nk;
            sflag = (nk < NPOST && cnt6 > (unsigned)Ceff) ? 1 : 0;
            skm[0] = kmask[0]; skm[1] = kmask[1]; skm[2] = kmask[2]; skm[3] = kmask[3];
            skm[4] = kmask[4]; skm[5] = kmask[5]; skm[6] = kmask[6]; skm[7] = kmask[7];
        }
    }
    if (tid == 0 && !mainValid) {
        snk = 0; sflag = 1;
        skm[0]=0; skm[1]=0; skm[2]=0; skm[3]=0; skm[4]=0; skm[5]=0; skm[6]=0; skm[7]=0;
    }
    __syncthreads();
    int nk = snk, flag = sflag;
    float4* out4 = (float4*)out;
    if (!flag) {
        int basepc[8];
        {
            int run = 0;
#pragma unroll
            for (int g = 0; g < 8; ++g) { basepc[g] = run; run += __popcll(skm[g]); }
        }
        int wv = tid >> 6, j = tid & 63;
#pragma unroll
        for (int gg = 0; gg < 2; ++gg) {
            int g = wv * 2 + gg;
            u64 km = skm[g];
            if ((km >> j) & 1ull) {
                int rank = basepc[g] + __popcll(km & ((1ull << j) - 1ull));
                if (rank < NPOST) out4[rank] = roiA[64 * g + j];
            }
        }
        for (int k = nk + tid; k < NPOST; k += 256) out4[k] = make_float4(0.f,0.f,0.f,0.f);
        return;
    }
    // ---------- exact fallback (gated; never taken on sane data) ----------
    unsigned M = cnt6 < (unsigned)CAP6 ? cnt6 : (unsigned)CAP6;
    for (unsigned i = tid; i < CAP6; i += 256) fb.lk[i] = (i < M) ? cand6[i] : ~0ULL;
    for (int r = tid; r < NPRE; r += 256) order6[r] = 0xFFFFFFFFu;
    __syncthreads();
    for (unsigned c = tid; c < M; c += 256) {
        u64 key = fb.lk[c];
        int rank = 0;
        for (unsigned j = 0; j < M; ++j) rank += (fb.lk[j] < key) ? 1 : 0;
        if (rank < NPRE) order6[rank] = (unsigned)key;
    }
    __syncthreads();
    for (int r = tid; r < NPRE; r += 256) {
        unsigned idx = order6[r];
        float4 b = make_float4(0.f, 0.f, 0.f, 0.f);
        if (idx < (unsigned)n) b = decode_box(anchor[idx], loc[idx], ih, iw);
        roi6[r] = b;
    }
    __syncthreads();
    if (tid < 64) {
        int lane = tid;
        int nk2 = 0;
        for (int i = 0; i < NPRE; i++) {
            float4 b = roi6[i];
            float hs = b.z - b.x, wd = b.w - b.y;
            if (!(hs >= MINSZ && wd >= MINSZ)) continue;
            float ab = hs * wd;
            bool sup = false;
            for (int base = 0; base < nk2 && !sup; base += 64) {
                int t = base + lane;
                bool s = false;
                if (t < nk2) {
                    float yy1 = fmaxf(b.x, fb.y1[t]);
                    float xx1 = fmaxf(b.y, fb.x1[t]);
                    float yy2 = fminf(b.z, fb.y2[t]);
                    float xx2 = fminf(b.w, fb.x2[t]);
                    float inter = fmaxf(yy2 - yy1, 0.0f) * fmaxf(xx2 - xx1, 0.0f);
                    float iou = inter / (fb.ar[t] + ab - inter);
                    s = iou > NMS_T;
                }
                sup = (__ballot(s) != 0ULL);
            }
            if (!sup) {
                if (lane == 0) {
                    fb.y1[nk2] = b.x; fb.x1[nk2] = b.y;
                    fb.y2[nk2] = b.z; fb.x2[nk2] = b.w; fb.ar[nk2] = ab;
                }
                nk2++;
                if (nk2 == NPOST) break;
            }
        }
        for (int k = lane; k < NPOST; k += 64) {
            float4 o = make_float4(0.f, 0.f, 0.f, 0.f);
            if (k < nk2) o = make_float4(fb.y1[k], fb.x1[k], fb.y2[k], fb.x2[k]);
            out4[k] = o;
        }
    }
}

extern "C" void kernel_launch(void* const* d_in, const int* in_sizes, int n_in,
                              void* d_out, int out_size, void* d_ws, size_t ws_size,
                              hipStream_t stream) {
    const float4* loc    = (const float4*)d_in[0];
    const float*  score  = (const float*)d_in[1];
    const float4* anchor = (const float4*)d_in[2];
    const int*    ph     = (const int*)d_in[3];
    const int*    pw     = (const int*)d_in[4];
    int n = in_sizes[1];

    char* ws = (char*)d_ws;
    u64*      cand6  = (u64*)(ws + OFF_CAND6);
    u64*      candA  = (u64*)(ws + OFF_CANDA);
    float4*   roiA   = (float4*)(ws + OFF_ROIA);
    u64*      vsup   = (u64*)(ws + OFF_VSUP);
    unsigned* order6 = (unsigned*)(ws + OFF_ORDER6);
    float4*   roi6   = (float4*)(ws + OFF_ROI6);
    u64*      gmat   = (u64*)(ws + OFF_GMAT);
    unsigned* slots  = (unsigned*)(ws + OFF_SLOT);
    unsigned* cnts   = (unsigned*)(ws + OFF_CNT);
    float* out = (float*)d_out;

    k_hist    <<<dim3(NSLOT), dim3(256), 0, stream>>>(score, n, slots, cnts);
    k_compact <<<dim3(128),   dim3(256), 0, stream>>>(loc, score, anchor, ph, pw, n, slots,
                                                      candA, cand6, cnts);
    k_rankmat <<<dim3(GRIDR), dim3(256), 0, stream>>>(loc, anchor, ph, pw, candA, cnts,
                                                      gmat, roiA, vsup);
    k_scan    <<<dim3(1),     dim3(256), 0, stream>>>(loc, anchor, ph, pw, n, cand6, cnts,
                                                      roiA, vsup, gmat, order6, roi6, out);
}

// Round 12
// 91.997 us; speedup vs baseline: 1.3526x; 1.0254x over previous
//
#include <hip/hip_runtime.h>
#include <stdint.h>

typedef unsigned long long u64;

#define NMS_T 0.7f
#define MINSZ 16.0f
#define NPRE 6000
#define NPOST 300
#define CA   384
#define NG   6          // groups of 64 = CA/64
#define CAPA 2048
#define CAP6 8192
#define NBIN 2048
#define NSLOT 32
#define GRIDR 9         // NG*CA/256 = 2304/256

// ---- workspace layout (bytes) ----
#define OFF_CAND6  0                          // CAP6*8  = 65536
#define OFF_CANDA  (OFF_CAND6 + CAP6*8)       // CAPA*8  = 16384
#define OFF_ORDER6 (OFF_CANDA + CAPA*8)       // NPRE*4  (fallback)
#define OFF_ROI6   (OFF_ORDER6 + NPRE*4)      // NPRE*16 (fallback)
#define OFF_GMAT   (OFF_ROI6 + NPRE*16)       // NG*CA*8 word-major gmat[w*CA+row]
#define OFF_SLOT   (OFF_GMAT + NG*CA*8)       // NSLOT*NBIN*4
#define OFF_CNT    (OFF_SLOT + NSLOT*NBIN*4)  // 32: [0]=cntA [1]=cnt6 [2]=done

__device__ __forceinline__ unsigned inv_key(float s) {
    unsigned u = __float_as_uint(s);
    unsigned k = (u & 0x80000000u) ? ~u : (u | 0x80000000u);
    return ~k;   // ascending inv == descending score
}

__device__ __forceinline__ float4 decode_box(const float4 a, const float4 l,
                                             float ih, float iw) {
    float h  = a.z - a.x;
    float w  = a.w - a.y;
    float cy = a.x + 0.5f * h;
    float cx = a.y + 0.5f * w;
    float ncy = l.x * h + cy;
    float ncx = l.y * w + cx;
    float nh  = expf(l.z) * h;
    float nw  = expf(l.w) * w;
    float y1 = fminf(fmaxf(ncy - 0.5f * nh, 0.0f), ih);
    float x1 = fminf(fmaxf(ncx - 0.5f * nw, 0.0f), iw);
    float y2 = fminf(fmaxf(ncy + 0.5f * nh, 0.0f), ih);
    float x2 = fminf(fmaxf(ncx + 0.5f * nw, 0.0f), iw);
    return make_float4(y1, x1, y2, x2);
}

__device__ __forceinline__ int sbin_of(float s) {
    int b = (int)(s * 2048.0f);
    b = b < 0 ? 0 : (b > 2047 ? 2047 : b);
    return 2047 - b;           // ascending = descending score
}

__device__ __forceinline__ u64 readlane64(u64 v, int lane) {
    unsigned lo = (unsigned)__builtin_amdgcn_readlane((int)(unsigned)v, lane);
    unsigned hi = (unsigned)__builtin_amdgcn_readlane((int)(unsigned)(v >> 32), lane);
    return ((u64)hi << 32) | (u64)lo;
}

// fast block scan of 2048-bin histogram (2 barriers): finds bins with ranks t0/t1
__device__ void fastscan2048(const unsigned* __restrict__ h, unsigned t0, unsigned t1,
                             unsigned* swave, unsigned* res) {
    int t = threadIdx.x;
    unsigned vals[8], s = 0;
#pragma unroll
    for (int j = 0; j < 8; ++j) { vals[j] = h[t * 8 + j]; s += vals[j]; }
    unsigned inc = s;
#pragma unroll
    for (int off = 1; off < 64; off <<= 1) {
        unsigned o = (unsigned)__shfl_up((int)inc, off, 64);
        if ((t & 63) >= off) inc += o;
    }
    if ((t & 63) == 63) swave[t >> 6] = inc;
    __syncthreads();
    unsigned wbase = 0;
    for (int w = 0; w < (t >> 6); ++w) wbase += swave[w];
    unsigned run = wbase + inc - s;
#pragma unroll
    for (int j = 0; j < 8; ++j) {
        unsigned c = vals[j];
        if (run < t0 && run + c >= t0) { res[0] = t * 8 + j; res[1] = run; }
        if (t1 && run < t1 && run + c >= t1) { res[2] = t * 8 + j; res[3] = run; }
        run += c;
    }
    __syncthreads();
}

// ---- 1: score-only histogram; 8x float4 register-batched loads ----
__global__ void __launch_bounds__(256) k_hist(const float* __restrict__ score, int n,
                                              unsigned* __restrict__ slots,
                                              unsigned* __restrict__ cnts) {
    __shared__ unsigned lh[NBIN];
    for (int b = threadIdx.x; b < NBIN; b += 256) lh[b] = 0;
    if (blockIdx.x == 0 && threadIdx.x < 8) cnts[threadIdx.x] = 0;
    __syncthreads();
    int gtid = blockIdx.x * 256 + threadIdx.x;
    int T = gridDim.x * 256;
    int n4 = n >> 2;
    const float4* s4 = (const float4*)score;
    for (int idx0 = gtid; idx0 < n4; idx0 += T * 8) {
        float4 v[8]; int ok[8];
#pragma unroll
        for (int k = 0; k < 8; ++k) {
            int idx = idx0 + k * T;
            ok[k] = idx < n4;
            v[k] = ok[k] ? s4[idx] : make_float4(0.f, 0.f, 0.f, 0.f);
        }
#pragma unroll
        for (int k = 0; k < 8; ++k) if (ok[k]) {
            atomicAdd(&lh[sbin_of(v[k].x)], 1u);
            atomicAdd(&lh[sbin_of(v[k].y)], 1u);
            atomicAdd(&lh[sbin_of(v[k].z)], 1u);
            atomicAdd(&lh[sbin_of(v[k].w)], 1u);
        }
    }
    for (int i = (n4 << 2) + gtid; i < n; i += T) atomicAdd(&lh[sbin_of(score[i])], 1u);
    __syncthreads();
    for (int b = threadIdx.x; b < NBIN; b += 256)
        slots[blockIdx.x * NBIN + b] = lh[b];
}

// ---- 2: thresholds -> mask-count -> block prefix -> winner decode+write ----
__global__ void __launch_bounds__(256) k_compact(
        const float4* __restrict__ loc, const float* __restrict__ score,
        const float4* __restrict__ anchor, const int* __restrict__ ph,
        const int* __restrict__ pw, int n, const unsigned* __restrict__ slots,
        u64* __restrict__ candA, u64* __restrict__ cand6, unsigned* __restrict__ cnts) {
    __shared__ unsigned hsum[NBIN];
    __shared__ unsigned psum[256];
    __shared__ unsigned res[8];
    __shared__ unsigned swave[8];
    __shared__ unsigned sbase[2];
    int tid = threadIdx.x;
    for (int b = tid; b < NBIN; b += 256) {
        unsigned s = 0;
#pragma unroll 4
        for (int sl = 0; sl < NSLOT; ++sl) s += slots[sl * NBIN + b];
        hsum[b] = s;
    }
    __syncthreads();
    fastscan2048(hsum, CA, NPRE, swave, res);   // res0 = bA, res2 = b6
    unsigned bA = res[0], b6 = res[2];
    float ih = (float)ph[0], iw = (float)pw[0];
    int gtid = blockIdx.x * 256 + tid;
    int T = gridDim.x * 256;
    int n4 = n >> 2;
    const float4* s4 = (const float4*)score;
    // phase 1: count (8x float4 batched)
    unsigned c6 = 0, cA = 0;
    for (int idx0 = gtid; idx0 < n4; idx0 += T * 8) {
        float4 v[8]; int ok[8];
#pragma unroll
        for (int k = 0; k < 8; ++k) {
            int idx = idx0 + k * T;
            ok[k] = idx < n4;
            v[k] = ok[k] ? s4[idx] : make_float4(0.f, 0.f, 0.f, 0.f);
        }
#pragma unroll
        for (int k = 0; k < 8; ++k) if (ok[k]) {
            unsigned h0 = (unsigned)sbin_of(v[k].x), h1 = (unsigned)sbin_of(v[k].y);
            unsigned h2 = (unsigned)sbin_of(v[k].z), h3 = (unsigned)sbin_of(v[k].w);
            c6 += (h0 <= b6) + (h1 <= b6) + (h2 <= b6) + (h3 <= b6);
            cA += (h0 <= bA) + (h1 <= bA) + (h2 <= bA) + (h3 <= bA);
        }
    }
    int ntail = n4 << 2;
    for (int i = ntail + gtid; i < n; i += T) {
        unsigned hb = (unsigned)sbin_of(score[i]);
        c6 += (hb <= b6);
        cA += (hb <= bA);
    }
    psum[tid] = (cA << 16) | c6;
    __syncthreads();
    for (int off = 1; off < 256; off <<= 1) {
        unsigned v = (tid >= off) ? psum[tid - off] : 0u;
        __syncthreads();
        psum[tid] += v;
        __syncthreads();
    }
    if (tid == 0) {
        unsigned tot = psum[255];
        sbase[0] = atomicAdd(&cnts[1], tot & 0xFFFFu);
        sbase[1] = atomicAdd(&cnts[0], tot >> 16);
    }
    __syncthreads();
    unsigned excl = (tid == 0) ? 0u : psum[tid - 1];
    unsigned pos6 = sbase[0] + (excl & 0xFFFFu);
    unsigned posA = sbase[1] + (excl >> 16);
    // phase 2: reload (L2-hot), decode winners (~6.5K total), write keys
    for (int idx0 = gtid; idx0 < n4; idx0 += T * 8) {
        float4 v[8]; int ok[8];
#pragma unroll
        for (int k = 0; k < 8; ++k) {
            int idx = idx0 + k * T;
            ok[k] = idx < n4;
            v[k] = ok[k] ? s4[idx] : make_float4(0.f, 0.f, 0.f, 0.f);
        }
#pragma unroll
        for (int k = 0; k < 8; ++k) if (ok[k]) {
            float sc[4] = {v[k].x, v[k].y, v[k].z, v[k].w};
            int ib = (idx0 + k * T) << 2;
#pragma unroll
            for (int c = 0; c < 4; ++c) {
                unsigned hb = (unsigned)sbin_of(sc[c]);
                if (hb <= b6) {
                    int i = ib + c;
                    float4 r = decode_box(anchor[i], loc[i], ih, iw);
                    bool valid = ((r.z - r.x) >= MINSZ) && ((r.w - r.y) >= MINSZ);
                    float ms = valid ? sc[c] : -__builtin_inff();
                    u64 key = ((u64)inv_key(ms) << 32) | (unsigned)i;
                    if (pos6 < CAP6) cand6[pos6] = key;
                    pos6++;
                    if (hb <= bA) {
                        if (posA < CAPA) candA[posA] = key;
                        posA++;
                    }
                }
            }
        }
    }
    for (int i = ntail + gtid; i < n; i += T) {
        float s = score[i];
        unsigned hb = (unsigned)sbin_of(s);
        if (hb <= b6) {
            float4 r = decode_box(anchor[i], loc[i], ih, iw);
            bool valid = ((r.z - r.x) >= MINSZ) && ((r.w - r.y) >= MINSZ);
            float ms = valid ? s : -__builtin_inff();
            u64 key = ((u64)inv_key(ms) << 32) | (unsigned)i;
            if (pos6 < CAP6) cand6[pos6] = key;
            pos6++;
            if (hb <= bA) {
                if (posA < CAPA) candA[posA] = key;
                posA++;
            }
        }
    }
}

struct SmFb {
    u64   lk[CAP6];                                // 64 KB
    float y1[NPOST], x1[NPOST], y2[NPOST], x2[NPOST], ar[NPOST];
};

// ---- 3: fused: counting-sort rank -> decode -> matrix slice -> (last block) scan ----
__global__ void __launch_bounds__(256) k_rankmat(
        const float4* __restrict__ loc, const float4* __restrict__ anchor,
        const int* __restrict__ ph, const int* __restrict__ pw, int n,
        const u64* __restrict__ candA, const u64* __restrict__ cand6,
        unsigned* __restrict__ cnts, u64* __restrict__ gmat,
        unsigned* __restrict__ order6, float4* __restrict__ roi6,
        float* __restrict__ out) {
    __shared__ u64 skey[CAPA];          // 16 KB
    __shared__ unsigned shist[NBIN];    // 8 KB
    __shared__ unsigned sprefix[NBIN];  // 8 KB
    __shared__ float4 sroi[CA];         // 6 KB
    __shared__ float  sarea[CA];        // 1.5 KB
    __shared__ unsigned svalid[CA / 32];
    __shared__ unsigned swave[8];
    __shared__ unsigned sInvLo;
    __shared__ int sIsLast;
    __shared__ u64 skm[NG];
    __shared__ int snk, sflag;
    __shared__ SmFb fb;                 // 64+6 KB (fallback only)
    int tid = threadIdx.x;
    unsigned cntA = cnts[0];
    bool mainValid = (cntA <= CAPA);
    unsigned MA = mainValid ? cntA : 0;
    float ih = (float)ph[0], iw = (float)pw[0];

    if (mainValid) {
        if (tid == 0) sInvLo = 0xFFFFFFFFu;
        for (int b = tid; b < NBIN; b += 256) shist[b] = 0;
        for (int r = tid; r < CA; r += 256) { sroi[r] = make_float4(0.f,0.f,0.f,0.f); sarea[r] = 0.f; }
        if (tid < CA / 32) svalid[tid] = 0;
        u64 kreg[8];
#pragma unroll
        for (int k = 0; k < 8; ++k) {
            unsigned i = tid + k * 256u;
            kreg[k] = (i < MA) ? candA[i] : ~0ULL;
        }
        unsigned mymin = 0xFFFFFFFFu;
#pragma unroll
        for (int k = 0; k < 8; ++k) {
            unsigned hi = (unsigned)(kreg[k] >> 32);
            mymin = mymin < hi ? mymin : hi;
        }
#pragma unroll
        for (int off = 32; off; off >>= 1) {
            unsigned o = (unsigned)__shfl_down((int)mymin, off, 64);
            mymin = mymin < o ? mymin : o;
        }
        if ((tid & 63) == 0) atomicMin(&sInvLo, mymin);
        __syncthreads();
        unsigned invLo = sInvLo;
#pragma unroll
        for (int k = 0; k < 8; ++k) {
            unsigned i = tid + k * 256u;
            if (i < MA) {
                unsigned d = ((unsigned)(kreg[k] >> 32) - invLo) >> 3;
                atomicAdd(&shist[d > 2047u ? 2047u : d], 1u);
            }
        }
        __syncthreads();
        {   // fast exclusive prefix into sprefix
            unsigned vals[8], s = 0;
#pragma unroll
            for (int j = 0; j < 8; ++j) { vals[j] = shist[tid * 8 + j]; s += vals[j]; }
            unsigned inc = s;
#pragma unroll
            for (int off = 1; off < 64; off <<= 1) {
                unsigned o = (unsigned)__shfl_up((int)inc, off, 64);
                if ((tid & 63) >= off) inc += o;
            }
            if ((tid & 63) == 63) swave[tid >> 6] = inc;
            __syncthreads();
            unsigned wbase = 0;
            for (int w = 0; w < (tid >> 6); ++w) wbase += swave[w];
            unsigned run = wbase + inc - s;
#pragma unroll
            for (int j = 0; j < 8; ++j) { sprefix[tid * 8 + j] = run; run += vals[j]; }
        }
        __syncthreads();
#pragma unroll
        for (int k = 0; k < 8; ++k) {
            unsigned i = tid + k * 256u;
            if (i < MA) {
                unsigned d = ((unsigned)(kreg[k] >> 32) - invLo) >> 3;
                d = d > 2047u ? 2047u : d;
                unsigned pos = atomicAdd(&sprefix[d], 1u);
                skey[pos] = kreg[k];
            }
        }
        __syncthreads();
#pragma unroll
        for (int k = 0; k < 8; ++k) {
            unsigned p = tid + k * 256u;
            if (p < MA) {
                u64 key = skey[p];
                unsigned d = ((unsigned)(key >> 32) - invLo) >> 3;
                d = d > 2047u ? 2047u : d;
                unsigned e = sprefix[d];
                unsigned s0 = e - shist[d];
                int rank = (int)s0;
                for (unsigned q = s0; q < e; ++q) rank += (skey[q] < key) ? 1 : 0;
                if (rank < CA) {
                    unsigned idx = (unsigned)key;
                    float4 b = decode_box(anchor[idx], loc[idx], ih, iw);
                    sroi[rank] = b;
                    sarea[rank] = (b.z - b.x) * (b.w - b.y);
                    if (((b.z - b.x) >= MINSZ) && ((b.w - b.y) >= MINSZ))
                        atomicOr(&svalid[rank >> 5], 1u << (rank & 31));
                }
            }
        }
        __syncthreads();
        // matrix slice: task = bid*256+tid; w = task/CA, row = task%CA
        {
            int task = blockIdx.x * 256 + tid;
            int w = task / CA;
            int row = task - w * CA;
            u64 bits = 0;
            int j0 = w << 6;
            if (j0 + 63 > row) {
                float4 b = sroi[row];
                float ab = sarea[row];
#pragma unroll 4
                for (int jj = 0; jj < 64; ++jj) {
                    int j = j0 + jj;
                    if (j > row) {
                        float4 c = sroi[j];
                        float yy1 = fmaxf(b.x, c.x);
                        float xx1 = fmaxf(b.y, c.y);
                        float yy2 = fminf(b.z, c.z);
                        float xx2 = fminf(b.w, c.w);
                        float inter = fmaxf(yy2 - yy1, 0.0f) * fmaxf(xx2 - xx1, 0.0f);
                        float iou = inter / (ab + sarea[j] - inter);  // ref op order
                        if (iou > NMS_T) bits |= (1ULL << jj);
                    }
                }
            }
            gmat[w * CA + row] = bits;
        }
    }
    // release our writes, count blocks done; last block runs the scan
    __threadfence();
    __syncthreads();
    if (tid == 0) {
        unsigned d = atomicAdd(&cnts[2], 1u);
        sIsLast = (d == GRIDR - 1);
    }
    __syncthreads();
    if (!sIsLast) return;
    __threadfence();   // acquire: other blocks' gmat writes now visible

    // ---- scan phase (this block only) ----
    unsigned cnt6 = cnts[1];
    int Ceff = (int)(cntA < (unsigned)CA ? cntA : (unsigned)CA);
    if (tid < 64 && mainValid) {
        u64 supfut[NG], curM[NG], nxtM[NG], kmask[NG];
#pragma unroll
        for (int w = 0; w < NG; ++w) {
            supfut[w] = ~(((u64)svalid[2 * w + 1] << 32) | (u64)svalid[2 * w]);
            kmask[w] = 0ull;
        }
#pragma unroll
        for (int w = 0; w < NG; ++w) curM[w] = gmat[w * CA + tid];
        int nk = 0;
        bool done = false;
#pragma unroll
        for (int g = 0; g < NG; ++g) {
            if (g < NG - 1) {
#pragma unroll
                for (int w = 0; w < NG; ++w) nxtM[w] = gmat[w * CA + 64 * (g + 1) + tid];
            }
            int base = 64 * g;
            if (!done && base < Ceff) {
                u64 bound = (Ceff - base >= 64) ? ~0ull : ((1ull << (Ceff - base)) - 1ull);
                u64 live = ~supfut[g] & bound;
                u64 km = 0;
                while (live) {
                    int b = (int)__builtin_ctzll(live);
                    km |= (1ull << b);
                    ++nk;
                    if (nk == NPOST) { done = true; break; }
                    u64 row = readlane64(curM[g], b);
                    live &= ~(row | (1ull << b));
                }
                kmask[g] = km;
                if (!done && g < NG - 1) {             // deferred cross-group fold
                    bool mk = ((km >> tid) & 1ull) != 0ull;
                    u64 c[NG];
#pragma unroll
                    for (int w = g + 1; w < NG; ++w) c[w] = mk ? curM[w] : 0ull;
#pragma unroll
                    for (int off = 1; off < 64; off <<= 1) {
#pragma unroll
                        for (int w = g + 1; w < NG; ++w) c[w] |= __shfl_xor(c[w], off, 64);
                    }
#pragma unroll
                    for (int w = g + 1; w < NG; ++w) supfut[w] |= c[w];
                }
            }
#pragma unroll
            for (int w = 0; w < NG; ++w) curM[w] = nxtM[w];
        }
        if (tid == 0) {
            snk = nk;
            sflag = (nk < NPOST && cnt6 > (unsigned)Ceff) ? 1 : 0;
#pragma unroll
            for (int g = 0; g < NG; ++g) skm[g] = kmask[g];
        }
    }
    if (tid == 0 && !mainValid) {
        snk = 0; sflag = 1;
#pragma unroll
        for (int g = 0; g < NG; ++g) skm[g] = 0ull;
    }
    __syncthreads();
    int nk = snk, flag = sflag;
    float4* out4 = (float4*)out;
    if (!flag) {
        int basepc[NG];
        {
            int run = 0;
#pragma unroll
            for (int g = 0; g < NG; ++g) { basepc[g] = run; run += __popcll(skm[g]); }
        }
        int wv = tid >> 6, j = tid & 63;
#pragma unroll
        for (int gg = 0; gg < 2; ++gg) {
            int g = wv + 4 * gg;
            if (g < NG) {
                u64 km = skm[g];
                if ((km >> j) & 1ull) {
                    int rank = basepc[g] + __popcll(km & ((1ull << j) - 1ull));
                    if (rank < NPOST) out4[rank] = sroi[64 * g + j];
                }
            }
        }
        for (int k = nk + tid; k < NPOST; k += 256) out4[k] = make_float4(0.f,0.f,0.f,0.f);
        return;
    }
    // ---------- exact fallback (gated; never taken on sane data) ----------
    unsigned M = cnt6 < (unsigned)CAP6 ? cnt6 : (unsigned)CAP6;
    for (unsigned i = tid; i < CAP6; i += 256) fb.lk[i] = (i < M) ? cand6[i] : ~0ULL;
    for (int r = tid; r < NPRE; r += 256) order6[r] = 0xFFFFFFFFu;
    __syncthreads();
    for (unsigned c = tid; c < M; c += 256) {
        u64 key = fb.lk[c];
        int rank = 0;
        for (unsigned j = 0; j < M; ++j) rank += (fb.lk[j] < key) ? 1 : 0;
        if (rank < NPRE) order6[rank] = (unsigned)key;
    }
    __syncthreads();
    for (int r = tid; r < NPRE; r += 256) {
        unsigned idx = order6[r];
        float4 b = make_float4(0.f, 0.f, 0.f, 0.f);
        if (idx < (unsigned)n) b = decode_box(anchor[idx], loc[idx], ih, iw);
        roi6[r] = b;
    }
    __syncthreads();
    if (tid < 64) {
        int lane = tid;
        int nk2 = 0;
        for (int i = 0; i < NPRE; i++) {
            float4 b = roi6[i];
            float hs = b.z - b.x, wd = b.w - b.y;
            if (!(hs >= MINSZ && wd >= MINSZ)) continue;
            float ab = hs * wd;
            bool sup = false;
            for (int base = 0; base < nk2 && !sup; base += 64) {
                int t = base + lane;
                bool s = false;
                if (t < nk2) {
                    float yy1 = fmaxf(b.x, fb.y1[t]);
                    float xx1 = fmaxf(b.y, fb.x1[t]);
                    float yy2 = fminf(b.z, fb.y2[t]);
                    float xx2 = fminf(b.w, fb.x2[t]);
                    float inter = fmaxf(yy2 - yy1, 0.0f) * fmaxf(xx2 - xx1, 0.0f);
                    float iou = inter / (fb.ar[t] + ab - inter);
                    s = iou > NMS_T;
                }
                sup = (__ballot(s) != 0ULL);
            }
            if (!sup) {
                if (lane == 0) {
                    fb.y1[nk2] = b.x; fb.x1[nk2] = b.y;
                    fb.y2[nk2] = b.z; fb.x2[nk2] = b.w; fb.ar[nk2] = ab;
                }
                nk2++;
                if (nk2 == NPOST) break;
            }
        }
        for (int k = lane; k < NPOST; k += 64) {
            float4 o = make_float4(0.f, 0.f, 0.f, 0.f);
            if (k < nk2) o = make_float4(fb.y1[k], fb.x1[k], fb.y2[k], fb.x2[k]);
            out4[k] = o;
        }
    }
}

extern "C" void kernel_launch(void* const* d_in, const int* in_sizes, int n_in,
                              void* d_out, int out_size, void* d_ws, size_t ws_size,
                              hipStream_t stream) {
    const float4* loc    = (const float4*)d_in[0];
    const float*  score  = (const float*)d_in[1];
    const float4* anchor = (const float4*)d_in[2];
    const int*    ph     = (const int*)d_in[3];
    const int*    pw     = (const int*)d_in[4];
    int n = in_sizes[1];

    char* ws = (char*)d_ws;
    u64*      cand6  = (u64*)(ws + OFF_CAND6);
    u64*      candA  = (u64*)(ws + OFF_CANDA);
    unsigned* order6 = (unsigned*)(ws + OFF_ORDER6);
    float4*   roi6   = (float4*)(ws + OFF_ROI6);
    u64*      gmat   = (u64*)(ws + OFF_GMAT);
    unsigned* slots  = (unsigned*)(ws + OFF_SLOT);
    unsigned* cnts   = (unsigned*)(ws + OFF_CNT);
    float* out = (float*)d_out;

    k_hist    <<<dim3(NSLOT), dim3(256), 0, stream>>>(score, n, slots, cnts);
    k_compact <<<dim3(128),   dim3(256), 0, stream>>>(loc, score, anchor, ph, pw, n, slots,
                                                      candA, cand6, cnts);
    k_rankmat <<<dim3(GRIDR), dim3(256), 0, stream>>>(loc, anchor, ph, pw, n, candA, cand6,
                                                      cnts, gmat, order6, roi6, out);
}

// Round 13
// 87.701 us; speedup vs baseline: 1.4188x; 1.0490x over previous
//
#include <hip/hip_runtime.h>
#include <stdint.h>

typedef unsigned long long u64;

#define NMS_T 0.7f
#define MINSZ 16.0f
#define NPRE 6000
#define NPOST 300
#define CA   384
#define NG   6          // groups of 64 = CA/64
#define CAPA 2048
#define CAP6 8192
#define NBIN 2048
#define NSLOT 32
#define GRIDR 9         // NG*CA/256 = 2304/256

// ---- workspace layout (bytes) ----
#define OFF_CAND6  0                          // CAP6*8  = 65536
#define OFF_CANDA  (OFF_CAND6 + CAP6*8)       // CAPA*8  = 16384
#define OFF_ORDER6 (OFF_CANDA + CAPA*8)       // NPRE*4  (fallback)
#define OFF_ROI6   (OFF_ORDER6 + NPRE*4)      // NPRE*16 (fallback)
#define OFF_GMAT   (OFF_ROI6 + NPRE*16)       // NG*CA*8 word-major gmat[w*CA+row]
#define OFF_SLOT   (OFF_GMAT + NG*CA*8)       // NSLOT*NBIN*4
#define OFF_CNT    (OFF_SLOT + NSLOT*NBIN*4)  // 32: [0]=cntA [1]=cnt6 [2]=done

__device__ __forceinline__ unsigned inv_key(float s) {
    unsigned u = __float_as_uint(s);
    unsigned k = (u & 0x80000000u) ? ~u : (u | 0x80000000u);
    return ~k;   // ascending inv == descending score
}

__device__ __forceinline__ float4 decode_box(const float4 a, const float4 l,
                                             float ih, float iw) {
    float h  = a.z - a.x;
    float w  = a.w - a.y;
    float cy = a.x + 0.5f * h;
    float cx = a.y + 0.5f * w;
    float ncy = l.x * h + cy;
    float ncx = l.y * w + cx;
    float nh  = expf(l.z) * h;
    float nw  = expf(l.w) * w;
    float y1 = fminf(fmaxf(ncy - 0.5f * nh, 0.0f), ih);
    float x1 = fminf(fmaxf(ncx - 0.5f * nw, 0.0f), iw);
    float y2 = fminf(fmaxf(ncy + 0.5f * nh, 0.0f), ih);
    float x2 = fminf(fmaxf(ncx + 0.5f * nw, 0.0f), iw);
    return make_float4(y1, x1, y2, x2);
}

__device__ __forceinline__ int sbin_of(float s) {
    int b = (int)(s * 2048.0f);
    b = b < 0 ? 0 : (b > 2047 ? 2047 : b);
    return 2047 - b;           // ascending = descending score
}

__device__ __forceinline__ u64 readlane64(u64 v, int lane) {
    unsigned lo = (unsigned)__builtin_amdgcn_readlane((int)(unsigned)v, lane);
    unsigned hi = (unsigned)__builtin_amdgcn_readlane((int)(unsigned)(v >> 32), lane);
    return ((u64)hi << 32) | (u64)lo;
}

// fast block scan of 2048-bin histogram (2 barriers): finds bins with ranks t0/t1
__device__ void fastscan2048(const unsigned* __restrict__ h, unsigned t0, unsigned t1,
                             unsigned* swave, unsigned* res) {
    int t = threadIdx.x;
    unsigned vals[8], s = 0;
#pragma unroll
    for (int j = 0; j < 8; ++j) { vals[j] = h[t * 8 + j]; s += vals[j]; }
    unsigned inc = s;
#pragma unroll
    for (int off = 1; off < 64; off <<= 1) {
        unsigned o = (unsigned)__shfl_up((int)inc, off, 64);
        if ((t & 63) >= off) inc += o;
    }
    if ((t & 63) == 63) swave[t >> 6] = inc;
    __syncthreads();
    unsigned wbase = 0;
    for (int w = 0; w < (t >> 6); ++w) wbase += swave[w];
    unsigned run = wbase + inc - s;
#pragma unroll
    for (int j = 0; j < 8; ++j) {
        unsigned c = vals[j];
        if (run < t0 && run + c >= t0) { res[0] = t * 8 + j; res[1] = run; }
        if (t1 && run < t1 && run + c >= t1) { res[2] = t * 8 + j; res[3] = run; }
        run += c;
    }
    __syncthreads();
}

// ---- 1: score-only histogram; 8x float4 register-batched loads ----
__global__ void __launch_bounds__(256) k_hist(const float* __restrict__ score, int n,
                                              unsigned* __restrict__ slots,
                                              unsigned* __restrict__ cnts) {
    __shared__ unsigned lh[NBIN];
    for (int b = threadIdx.x; b < NBIN; b += 256) lh[b] = 0;
    if (blockIdx.x == 0 && threadIdx.x < 8) cnts[threadIdx.x] = 0;
    __syncthreads();
    int gtid = blockIdx.x * 256 + threadIdx.x;
    int T = gridDim.x * 256;
    int n4 = n >> 2;
    const float4* s4 = (const float4*)score;
    for (int idx0 = gtid; idx0 < n4; idx0 += T * 8) {
        float4 v[8]; int ok[8];
#pragma unroll
        for (int k = 0; k < 8; ++k) {
            int idx = idx0 + k * T;
            ok[k] = idx < n4;
            v[k] = ok[k] ? s4[idx] : make_float4(0.f, 0.f, 0.f, 0.f);
        }
#pragma unroll
        for (int k = 0; k < 8; ++k) if (ok[k]) {
            atomicAdd(&lh[sbin_of(v[k].x)], 1u);
            atomicAdd(&lh[sbin_of(v[k].y)], 1u);
            atomicAdd(&lh[sbin_of(v[k].z)], 1u);
            atomicAdd(&lh[sbin_of(v[k].w)], 1u);
        }
    }
    for (int i = (n4 << 2) + gtid; i < n; i += T) atomicAdd(&lh[sbin_of(score[i])], 1u);
    __syncthreads();
    for (int b = threadIdx.x; b < NBIN; b += 256)
        slots[blockIdx.x * NBIN + b] = lh[b];
}

// ---- 2: thresholds -> mask-count -> block prefix -> winner decode+write ----
__global__ void __launch_bounds__(256) k_compact(
        const float4* __restrict__ loc, const float* __restrict__ score,
        const float4* __restrict__ anchor, const int* __restrict__ ph,
        const int* __restrict__ pw, int n, const unsigned* __restrict__ slots,
        u64* __restrict__ candA, u64* __restrict__ cand6, unsigned* __restrict__ cnts) {
    __shared__ unsigned hsum[NBIN];
    __shared__ unsigned psum[256];
    __shared__ unsigned res[8];
    __shared__ unsigned swave[8];
    __shared__ unsigned sbase[2];
    int tid = threadIdx.x;
    for (int b = tid; b < NBIN; b += 256) {
        unsigned s = 0;
#pragma unroll 4
        for (int sl = 0; sl < NSLOT; ++sl) s += slots[sl * NBIN + b];
        hsum[b] = s;
    }
    __syncthreads();
    fastscan2048(hsum, CA, NPRE, swave, res);   // res0 = bA, res2 = b6
    unsigned bA = res[0], b6 = res[2];
    float ih = (float)ph[0], iw = (float)pw[0];
    int gtid = blockIdx.x * 256 + tid;
    int T = gridDim.x * 256;
    int n4 = n >> 2;
    const float4* s4 = (const float4*)score;
    // phase 1: count (8x float4 batched)
    unsigned c6 = 0, cA = 0;
    for (int idx0 = gtid; idx0 < n4; idx0 += T * 8) {
        float4 v[8]; int ok[8];
#pragma unroll
        for (int k = 0; k < 8; ++k) {
            int idx = idx0 + k * T;
            ok[k] = idx < n4;
            v[k] = ok[k] ? s4[idx] : make_float4(0.f, 0.f, 0.f, 0.f);
        }
#pragma unroll
        for (int k = 0; k < 8; ++k) if (ok[k]) {
            unsigned h0 = (unsigned)sbin_of(v[k].x), h1 = (unsigned)sbin_of(v[k].y);
            unsigned h2 = (unsigned)sbin_of(v[k].z), h3 = (unsigned)sbin_of(v[k].w);
            c6 += (h0 <= b6) + (h1 <= b6) + (h2 <= b6) + (h3 <= b6);
            cA += (h0 <= bA) + (h1 <= bA) + (h2 <= bA) + (h3 <= bA);
        }
    }
    int ntail = n4 << 2;
    for (int i = ntail + gtid; i < n; i += T) {
        unsigned hb = (unsigned)sbin_of(score[i]);
        c6 += (hb <= b6);
        cA += (hb <= bA);
    }
    psum[tid] = (cA << 16) | c6;
    __syncthreads();
    for (int off = 1; off < 256; off <<= 1) {
        unsigned v = (tid >= off) ? psum[tid - off] : 0u;
        __syncthreads();
        psum[tid] += v;
        __syncthreads();
    }
    if (tid == 0) {
        unsigned tot = psum[255];
        sbase[0] = atomicAdd(&cnts[1], tot & 0xFFFFu);
        sbase[1] = atomicAdd(&cnts[0], tot >> 16);
    }
    __syncthreads();
    unsigned excl = (tid == 0) ? 0u : psum[tid - 1];
    unsigned pos6 = sbase[0] + (excl & 0xFFFFu);
    unsigned posA = sbase[1] + (excl >> 16);
    // phase 2: reload (L2-hot), decode winners (~6.5K total), write keys
    for (int idx0 = gtid; idx0 < n4; idx0 += T * 8) {
        float4 v[8]; int ok[8];
#pragma unroll
        for (int k = 0; k < 8; ++k) {
            int idx = idx0 + k * T;
            ok[k] = idx < n4;
            v[k] = ok[k] ? s4[idx] : make_float4(0.f, 0.f, 0.f, 0.f);
        }
#pragma unroll
        for (int k = 0; k < 8; ++k) if (ok[k]) {
            float sc[4] = {v[k].x, v[k].y, v[k].z, v[k].w};
            int ib = (idx0 + k * T) << 2;
#pragma unroll
            for (int c = 0; c < 4; ++c) {
                unsigned hb = (unsigned)sbin_of(sc[c]);
                if (hb <= b6) {
                    int i = ib + c;
                    float4 r = decode_box(anchor[i], loc[i], ih, iw);
                    bool valid = ((r.z - r.x) >= MINSZ) && ((r.w - r.y) >= MINSZ);
                    float ms = valid ? sc[c] : -__builtin_inff();
                    u64 key = ((u64)inv_key(ms) << 32) | (unsigned)i;
                    if (pos6 < CAP6) cand6[pos6] = key;
                    pos6++;
                    if (hb <= bA) {
                        if (posA < CAPA) candA[posA] = key;
                        posA++;
                    }
                }
            }
        }
    }
    for (int i = ntail + gtid; i < n; i += T) {
        float s = score[i];
        unsigned hb = (unsigned)sbin_of(s);
        if (hb <= b6) {
            float4 r = decode_box(anchor[i], loc[i], ih, iw);
            bool valid = ((r.z - r.x) >= MINSZ) && ((r.w - r.y) >= MINSZ);
            float ms = valid ? s : -__builtin_inff();
            u64 key = ((u64)inv_key(ms) << 32) | (unsigned)i;
            if (pos6 < CAP6) cand6[pos6] = key;
            pos6++;
            if (hb <= bA) {
                if (posA < CAPA) candA[posA] = key;
                posA++;
            }
        }
    }
}

struct SmFb {
    u64   lk[CAP6];                                // 64 KB
    float y1[NPOST], x1[NPOST], y2[NPOST], x2[NPOST], ar[NPOST];
};

// ---- 3: fused: counting-sort rank -> decode -> matrix slice -> (last block) scan ----
__global__ void __launch_bounds__(256) k_rankmat(
        const float4* __restrict__ loc, const float4* __restrict__ anchor,
        const int* __restrict__ ph, const int* __restrict__ pw, int n,
        const u64* __restrict__ candA, const u64* __restrict__ cand6,
        unsigned* __restrict__ cnts, u64* __restrict__ gmat,
        unsigned* __restrict__ order6, float4* __restrict__ roi6,
        float* __restrict__ out) {
    __shared__ u64 skey[CAPA];          // 16 KB
    __shared__ unsigned shist[NBIN];    // 8 KB
    __shared__ unsigned sprefix[NBIN];  // 8 KB
    __shared__ float4 sroi[CA];         // 6 KB
    __shared__ float  sarea[CA];        // 1.5 KB
    __shared__ unsigned svalid[CA / 32];
    __shared__ unsigned swave[8];
    __shared__ unsigned sInvLo;
    __shared__ int sIsLast;
    __shared__ u64 skm[NG];
    __shared__ int snk, sflag;
    __shared__ SmFb fb;                 // fallback only
    int tid = threadIdx.x;
    unsigned cntA = cnts[0];
    bool mainValid = (cntA <= CAPA);
    unsigned MA = mainValid ? cntA : 0;
    float ih = (float)ph[0], iw = (float)pw[0];

    if (mainValid) {
        if (tid == 0) sInvLo = 0xFFFFFFFFu;
        for (int b = tid; b < NBIN; b += 256) shist[b] = 0;
        for (int r = tid; r < CA; r += 256) { sroi[r] = make_float4(0.f,0.f,0.f,0.f); sarea[r] = 0.f; }
        if (tid < CA / 32) svalid[tid] = 0;
        u64 kreg[8];
#pragma unroll
        for (int k = 0; k < 8; ++k) {
            unsigned i = tid + k * 256u;
            kreg[k] = (i < MA) ? candA[i] : ~0ULL;
        }
        unsigned mymin = 0xFFFFFFFFu;
#pragma unroll
        for (int k = 0; k < 8; ++k) {
            unsigned hi = (unsigned)(kreg[k] >> 32);
            mymin = mymin < hi ? mymin : hi;
        }
#pragma unroll
        for (int off = 32; off; off >>= 1) {
            unsigned o = (unsigned)__shfl_down((int)mymin, off, 64);
            mymin = mymin < o ? mymin : o;
        }
        if ((tid & 63) == 0) atomicMin(&sInvLo, mymin);
        __syncthreads();
        unsigned invLo = sInvLo;
#pragma unroll
        for (int k = 0; k < 8; ++k) {
            unsigned i = tid + k * 256u;
            if (i < MA) {
                unsigned d = ((unsigned)(kreg[k] >> 32) - invLo) >> 3;
                atomicAdd(&shist[d > 2047u ? 2047u : d], 1u);
            }
        }
        __syncthreads();
        {   // fast exclusive prefix into sprefix
            unsigned vals[8], s = 0;
#pragma unroll
            for (int j = 0; j < 8; ++j) { vals[j] = shist[tid * 8 + j]; s += vals[j]; }
            unsigned inc = s;
#pragma unroll
            for (int off = 1; off < 64; off <<= 1) {
                unsigned o = (unsigned)__shfl_up((int)inc, off, 64);
                if ((tid & 63) >= off) inc += o;
            }
            if ((tid & 63) == 63) swave[tid >> 6] = inc;
            __syncthreads();
            unsigned wbase = 0;
            for (int w = 0; w < (tid >> 6); ++w) wbase += swave[w];
            unsigned run = wbase + inc - s;
#pragma unroll
            for (int j = 0; j < 8; ++j) { sprefix[tid * 8 + j] = run; run += vals[j]; }
        }
        __syncthreads();
#pragma unroll
        for (int k = 0; k < 8; ++k) {
            unsigned i = tid + k * 256u;
            if (i < MA) {
                unsigned d = ((unsigned)(kreg[k] >> 32) - invLo) >> 3;
                d = d > 2047u ? 2047u : d;
                unsigned pos = atomicAdd(&sprefix[d], 1u);
                skey[pos] = kreg[k];
            }
        }
        __syncthreads();
#pragma unroll
        for (int k = 0; k < 8; ++k) {
            unsigned p = tid + k * 256u;
            if (p < MA) {
                u64 key = skey[p];
                unsigned d = ((unsigned)(key >> 32) - invLo) >> 3;
                d = d > 2047u ? 2047u : d;
                unsigned e = sprefix[d];
                unsigned s0 = e - shist[d];
                int rank = (int)s0;
                for (unsigned q = s0; q < e; ++q) rank += (skey[q] < key) ? 1 : 0;
                if (rank < CA) {
                    unsigned idx = (unsigned)key;
                    float4 b = decode_box(anchor[idx], loc[idx], ih, iw);
                    sroi[rank] = b;
                    sarea[rank] = (b.z - b.x) * (b.w - b.y);
                    if (((b.z - b.x) >= MINSZ) && ((b.w - b.y) >= MINSZ))
                        atomicOr(&svalid[rank >> 5], 1u << (rank & 31));
                }
            }
        }
        __syncthreads();
        // matrix slice: task = bid*256+tid; w = task/CA, row = task%CA
        {
            int task = blockIdx.x * 256 + tid;
            int w = task / CA;
            int row = task - w * CA;
            u64 bits = 0;
            int j0 = w << 6;
            if (j0 + 63 > row) {
                float4 b = sroi[row];
                float ab = sarea[row];
#pragma unroll 4
                for (int jj = 0; jj < 64; ++jj) {
                    int j = j0 + jj;
                    if (j > row) {
                        float4 c = sroi[j];
                        float yy1 = fmaxf(b.x, c.x);
                        float xx1 = fmaxf(b.y, c.y);
                        float yy2 = fminf(b.z, c.z);
                        float xx2 = fminf(b.w, c.w);
                        float inter = fmaxf(yy2 - yy1, 0.0f) * fmaxf(xx2 - xx1, 0.0f);
                        float iou = inter / (ab + sarea[j] - inter);  // ref op order
                        if (iou > NMS_T) bits |= (1ULL << jj);
                    }
                }
            }
            gmat[w * CA + row] = bits;
        }
    }
    // release our writes, count blocks done; last block runs the scan
    __threadfence();
    __syncthreads();
    if (tid == 0) {
        unsigned d = atomicAdd(&cnts[2], 1u);
        sIsLast = (d == GRIDR - 1);
    }
    __syncthreads();
    if (!sIsLast) return;
    __threadfence();   // acquire: other blocks' gmat writes now visible

    // ---- scan phase (this block only): 4-wide speculative batches ----
    unsigned cnt6 = cnts[1];
    int Ceff = (int)(cntA < (unsigned)CA ? cntA : (unsigned)CA);
    if (tid < 64 && mainValid) {
        u64 supfut[NG], curM[NG], nxtM[NG], kmask[NG];
#pragma unroll
        for (int w = 0; w < NG; ++w) {
            supfut[w] = ~(((u64)svalid[2 * w + 1] << 32) | (u64)svalid[2 * w]);
            kmask[w] = 0ull;
        }
#pragma unroll
        for (int w = 0; w < NG; ++w) curM[w] = gmat[w * CA + tid];
        int nk = 0;
        bool done = false;
#pragma unroll
        for (int g = 0; g < NG; ++g) {
            if (g < NG - 1) {
#pragma unroll
                for (int w = 0; w < NG; ++w) nxtM[w] = gmat[w * CA + 64 * (g + 1) + tid];
            }
            int base = 64 * g;
            if (!done && base < Ceff) {
                u64 bound = (Ceff - base >= 64) ? ~0ull : ((1ull << (Ceff - base)) - 1ull);
                u64 live = ~supfut[g] & bound;
                u64 km = 0;
                while (live) {
                    // extract up to 4 candidate bits (register-only)
                    u64 t = live;
                    int b0 = (int)__builtin_ctzll(t); t &= t - 1;
                    int b1 = t ? (int)__builtin_ctzll(t) : -1; if (t) t &= t - 1;
                    int b2 = t ? (int)__builtin_ctzll(t) : -1; if (t) t &= t - 1;
                    int b3 = t ? (int)__builtin_ctzll(t) : -1;
                    // fetch all rows' word g together (independent readlanes)
                    u64 r0 = readlane64(curM[g], b0);
                    u64 r1 = (b1 >= 0) ? readlane64(curM[g], b1) : 0ull;
                    u64 r2 = (b2 >= 0) ? readlane64(curM[g], b2) : 0ull;
                    u64 r3 = (b3 >= 0) ? readlane64(curM[g], b3) : 0ull;
                    // exact greedy resolve among the batch (ordered, NPOST-trimmed)
                    u64 supx = 0ull, proc = 0ull;
                    proc |= 1ull << b0;                     // b0 always kept (live => unsuppressed)
                    km |= 1ull << b0; supx |= r0; ++nk;
                    if (nk == NPOST) done = true;
                    if (!done && b1 >= 0) {
                        proc |= 1ull << b1;
                        if (!((supx >> b1) & 1ull)) {
                            km |= 1ull << b1; supx |= r1; ++nk;
                            if (nk == NPOST) done = true;
                        }
                    }
                    if (!done && b2 >= 0) {
                        proc |= 1ull << b2;
                        if (!((supx >> b2) & 1ull)) {
                            km |= 1ull << b2; supx |= r2; ++nk;
                            if (nk == NPOST) done = true;
                        }
                    }
                    if (!done && b3 >= 0) {
                        proc |= 1ull << b3;
                        if (!((supx >> b3) & 1ull)) {
                            km |= 1ull << b3; supx |= r3; ++nk;
                            if (nk == NPOST) done = true;
                        }
                    }
                    live &= ~(proc | supx);
                    if (done) break;
                }
                kmask[g] = km;
                if (!done && g < NG - 1) {             // deferred cross-group fold
                    bool mk = ((km >> tid) & 1ull) != 0ull;
                    u64 c[NG];
#pragma unroll
                    for (int w = g + 1; w < NG; ++w) c[w] = mk ? curM[w] : 0ull;
#pragma unroll
                    for (int off = 1; off < 64; off <<= 1) {
#pragma unroll
                        for (int w = g + 1; w < NG; ++w) c[w] |= __shfl_xor(c[w], off, 64);
                    }
#pragma unroll
                    for (int w = g + 1; w < NG; ++w) supfut[w] |= c[w];
                }
            }
#pragma unroll
            for (int w = 0; w < NG; ++w) curM[w] = nxtM[w];
        }
        if (tid == 0) {
            snk = nk;
            sflag = (nk < NPOST && cnt6 > (unsigned)Ceff) ? 1 : 0;
#pragma unroll
            for (int g = 0; g < NG; ++g) skm[g] = kmask[g];
        }
    }
    if (tid == 0 && !mainValid) {
        snk = 0; sflag = 1;
#pragma unroll
        for (int g = 0; g < NG; ++g) skm[g] = 0ull;
    }
    __syncthreads();
    int nk = snk, flag = sflag;
    float4* out4 = (float4*)out;
    if (!flag) {
        int basepc[NG];
        {
            int run = 0;
#pragma unroll
            for (int g = 0; g < NG; ++g) { basepc[g] = run; run += __popcll(skm[g]); }
        }
        int wv = tid >> 6, j = tid & 63;
#pragma unroll
        for (int gg = 0; gg < 2; ++gg) {
            int g = wv + 4 * gg;
            if (g < NG) {
                u64 km = skm[g];
                if ((km >> j) & 1ull) {
                    int rank = basepc[g] + __popcll(km & ((1ull << j) - 1ull));
                    if (rank < NPOST) out4[rank] = sroi[64 * g + j];
                }
            }
        }
        for (int k = nk + tid; k < NPOST; k += 256) out4[k] = make_float4(0.f,0.f,0.f,0.f);
        return;
    }
    // ---------- exact fallback (gated; never taken on sane data) ----------
    unsigned M = cnt6 < (unsigned)CAP6 ? cnt6 : (unsigned)CAP6;
    for (unsigned i = tid; i < CAP6; i += 256) fb.lk[i] = (i < M) ? cand6[i] : ~0ULL;
    for (int r = tid; r < NPRE; r += 256) order6[r] = 0xFFFFFFFFu;
    __syncthreads();
    for (unsigned c = tid; c < M; c += 256) {
        u64 key = fb.lk[c];
        int rank = 0;
        for (unsigned j = 0; j < M; ++j) rank += (fb.lk[j] < key) ? 1 : 0;
        if (rank < NPRE) order6[rank] = (unsigned)key;
    }
    __syncthreads();
    for (int r = tid; r < NPRE; r += 256) {
        unsigned idx = order6[r];
        float4 b = make_float4(0.f, 0.f, 0.f, 0.f);
        if (idx < (unsigned)n) b = decode_box(anchor[idx], loc[idx], ih, iw);
        roi6[r] = b;
    }
    __syncthreads();
    if (tid < 64) {
        int lane = tid;
        int nk2 = 0;
        for (int i = 0; i < NPRE; i++) {
            float4 b = roi6[i];
            float hs = b.z - b.x, wd = b.w - b.y;
            if (!(hs >= MINSZ && wd >= MINSZ)) continue;
            float ab = hs * wd;
            bool sup = false;
            for (int base = 0; base < nk2 && !sup; base += 64) {
                int t = base + lane;
                bool s = false;
                if (t < nk2) {
                    float yy1 = fmaxf(b.x, fb.y1[t]);
                    float xx1 = fmaxf(b.y, fb.x1[t]);
                    float yy2 = fminf(b.z, fb.y2[t]);
                    float xx2 = fminf(b.w, fb.x2[t]);
                    float inter = fmaxf(yy2 - yy1, 0.0f) * fmaxf(xx2 - xx1, 0.0f);
                    float iou = inter / (fb.ar[t] + ab - inter);
                    s = iou > NMS_T;
                }
                sup = (__ballot(s) != 0ULL);
            }
            if (!sup) {
                if (lane == 0) {
                    fb.y1[nk2] = b.x; fb.x1[nk2] = b.y;
                    fb.y2[nk2] = b.z; fb.x2[nk2] = b.w; fb.ar[nk2] = ab;
                }
                nk2++;
                if (nk2 == NPOST) break;
            }
        }
        for (int k = lane; k < NPOST; k += 64) {
            float4 o = make_float4(0.f, 0.f, 0.f, 0.f);
            if (k < nk2) o = make_float4(fb.y1[k], fb.x1[k], fb.y2[k], fb.x2[k]);
            out4[k] = o;
        }
    }
}

extern "C" void kernel_launch(void* const* d_in, const int* in_sizes, int n_in,
                              void* d_out, int out_size, void* d_ws, size_t ws_size,
                              hipStream_t stream) {
    const float4* loc    = (const float4*)d_in[0];
    const float*  score  = (const float*)d_in[1];
    const float4* anchor = (const float4*)d_in[2];
    const int*    ph     = (const int*)d_in[3];
    const int*    pw     = (const int*)d_in[4];
    int n = in_sizes[1];

    char* ws = (char*)d_ws;
    u64*      cand6  = (u64*)(ws + OFF_CAND6);
    u64*      candA  = (u64*)(ws + OFF_CANDA);
    unsigned* order6 = (unsigned*)(ws + OFF_ORDER6);
    float4*   roi6   = (float4*)(ws + OFF_ROI6);
    u64*      gmat   = (u64*)(ws + OFF_GMAT);
    unsigned* slots  = (unsigned*)(ws + OFF_SLOT);
    unsigned* cnts   = (unsigned*)(ws + OFF_CNT);
    float* out = (float*)d_out;

    k_hist    <<<dim3(NSLOT), dim3(256), 0, stream>>>(score, n, slots, cnts);
    k_compact <<<dim3(128),   dim3(256), 0, stream>>>(loc, score, anchor, ph, pw, n, slots,
                                                      candA, cand6, cnts);
    k_rankmat <<<dim3(GRIDR), dim3(256), 0, stream>>>(loc, anchor, ph, pw, n, candA, cand6,
                                                      cnts, gmat, order6, roi6, out);
}

// Round 14
// 74.465 us; speedup vs baseline: 1.6710x; 1.1778x over previous
//
#include <hip/hip_runtime.h>
#include <stdint.h>

typedef unsigned long long u64;

#define NMS_T 0.7f
#define MINSZ 16.0f
#define NPRE 6000
#define NPOST 300
#define CA   384
#define NG   6          // groups of 64 = CA/64
#define CAPA 2048
#define CAP6 8192
#define NBIN 2048
#define NSLOT 32
#define GRIDR 9         // NG*CA/256 = 2304/256

// ---- workspace layout (bytes) ----
#define OFF_CAND6  0                          // CAP6*8  = 65536
#define OFF_CANDA  (OFF_CAND6 + CAP6*8)       // CAPA*8  = 16384
#define OFF_ORDER6 (OFF_CANDA + CAPA*8)       // NPRE*4  (fallback)
#define OFF_ROI6   (OFF_ORDER6 + NPRE*4)      // NPRE*16 (fallback)
#define OFF_GMAT   (OFF_ROI6 + NPRE*16)       // NG*CA*8 TRANSPOSED: gmatT[gr*CA+col]
#define OFF_SLOT   (OFF_GMAT + NG*CA*8)       // NSLOT*NBIN*4
#define OFF_CNT    (OFF_SLOT + NSLOT*NBIN*4)  // 32: [0]=cntA [1]=cnt6 [2]=done

__device__ __forceinline__ unsigned inv_key(float s) {
    unsigned u = __float_as_uint(s);
    unsigned k = (u & 0x80000000u) ? ~u : (u | 0x80000000u);
    return ~k;   // ascending inv == descending score
}

__device__ __forceinline__ float4 decode_box(const float4 a, const float4 l,
                                             float ih, float iw) {
    float h  = a.z - a.x;
    float w  = a.w - a.y;
    float cy = a.x + 0.5f * h;
    float cx = a.y + 0.5f * w;
    float ncy = l.x * h + cy;
    float ncx = l.y * w + cx;
    float nh  = expf(l.z) * h;
    float nw  = expf(l.w) * w;
    float y1 = fminf(fmaxf(ncy - 0.5f * nh, 0.0f), ih);
    float x1 = fminf(fmaxf(ncx - 0.5f * nw, 0.0f), iw);
    float y2 = fminf(fmaxf(ncy + 0.5f * nh, 0.0f), ih);
    float x2 = fminf(fmaxf(ncx + 0.5f * nw, 0.0f), iw);
    return make_float4(y1, x1, y2, x2);
}

__device__ __forceinline__ int sbin_of(float s) {
    int b = (int)(s * 2048.0f);
    b = b < 0 ? 0 : (b > 2047 ? 2047 : b);
    return 2047 - b;           // ascending = descending score
}

// fast block scan of 2048-bin histogram (2 barriers): finds bins with ranks t0/t1
__device__ void fastscan2048(const unsigned* __restrict__ h, unsigned t0, unsigned t1,
                             unsigned* swave, unsigned* res) {
    int t = threadIdx.x;
    unsigned vals[8], s = 0;
#pragma unroll
    for (int j = 0; j < 8; ++j) { vals[j] = h[t * 8 + j]; s += vals[j]; }
    unsigned inc = s;
#pragma unroll
    for (int off = 1; off < 64; off <<= 1) {
        unsigned o = (unsigned)__shfl_up((int)inc, off, 64);
        if ((t & 63) >= off) inc += o;
    }
    if ((t & 63) == 63) swave[t >> 6] = inc;
    __syncthreads();
    unsigned wbase = 0;
    for (int w = 0; w < (t >> 6); ++w) wbase += swave[w];
    unsigned run = wbase + inc - s;
#pragma unroll
    for (int j = 0; j < 8; ++j) {
        unsigned c = vals[j];
        if (run < t0 && run + c >= t0) { res[0] = t * 8 + j; res[1] = run; }
        if (t1 && run < t1 && run + c >= t1) { res[2] = t * 8 + j; res[3] = run; }
        run += c;
    }
    __syncthreads();
}

// ---- 1: score-only histogram; 8x float4 register-batched loads ----
__global__ void __launch_bounds__(256) k_hist(const float* __restrict__ score, int n,
                                              unsigned* __restrict__ slots,
                                              unsigned* __restrict__ cnts) {
    __shared__ unsigned lh[NBIN];
    for (int b = threadIdx.x; b < NBIN; b += 256) lh[b] = 0;
    if (blockIdx.x == 0 && threadIdx.x < 8) cnts[threadIdx.x] = 0;
    __syncthreads();
    int gtid = blockIdx.x * 256 + threadIdx.x;
    int T = gridDim.x * 256;
    int n4 = n >> 2;
    const float4* s4 = (const float4*)score;
    for (int idx0 = gtid; idx0 < n4; idx0 += T * 8) {
        float4 v[8]; int ok[8];
#pragma unroll
        for (int k = 0; k < 8; ++k) {
            int idx = idx0 + k * T;
            ok[k] = idx < n4;
            v[k] = ok[k] ? s4[idx] : make_float4(0.f, 0.f, 0.f, 0.f);
        }
#pragma unroll
        for (int k = 0; k < 8; ++k) if (ok[k]) {
            atomicAdd(&lh[sbin_of(v[k].x)], 1u);
            atomicAdd(&lh[sbin_of(v[k].y)], 1u);
            atomicAdd(&lh[sbin_of(v[k].z)], 1u);
            atomicAdd(&lh[sbin_of(v[k].w)], 1u);
        }
    }
    for (int i = (n4 << 2) + gtid; i < n; i += T) atomicAdd(&lh[sbin_of(score[i])], 1u);
    __syncthreads();
    for (int b = threadIdx.x; b < NBIN; b += 256)
        slots[blockIdx.x * NBIN + b] = lh[b];
}

// ---- 2: thresholds -> mask-count -> block prefix -> winner decode+write ----
__global__ void __launch_bounds__(256) k_compact(
        const float4* __restrict__ loc, const float* __restrict__ score,
        const float4* __restrict__ anchor, const int* __restrict__ ph,
        const int* __restrict__ pw, int n, const unsigned* __restrict__ slots,
        u64* __restrict__ candA, u64* __restrict__ cand6, unsigned* __restrict__ cnts) {
    __shared__ unsigned hsum[NBIN];
    __shared__ unsigned psum[256];
    __shared__ unsigned res[8];
    __shared__ unsigned swave[8];
    __shared__ unsigned sbase[2];
    int tid = threadIdx.x;
    for (int b = tid; b < NBIN; b += 256) {
        unsigned s = 0;
#pragma unroll 4
        for (int sl = 0; sl < NSLOT; ++sl) s += slots[sl * NBIN + b];
        hsum[b] = s;
    }
    __syncthreads();
    fastscan2048(hsum, CA, NPRE, swave, res);   // res0 = bA, res2 = b6
    unsigned bA = res[0], b6 = res[2];
    float ih = (float)ph[0], iw = (float)pw[0];
    int gtid = blockIdx.x * 256 + tid;
    int T = gridDim.x * 256;
    int n4 = n >> 2;
    const float4* s4 = (const float4*)score;
    // phase 1: count (8x float4 batched)
    unsigned c6 = 0, cA = 0;
    for (int idx0 = gtid; idx0 < n4; idx0 += T * 8) {
        float4 v[8]; int ok[8];
#pragma unroll
        for (int k = 0; k < 8; ++k) {
            int idx = idx0 + k * T;
            ok[k] = idx < n4;
            v[k] = ok[k] ? s4[idx] : make_float4(0.f, 0.f, 0.f, 0.f);
        }
#pragma unroll
        for (int k = 0; k < 8; ++k) if (ok[k]) {
            unsigned h0 = (unsigned)sbin_of(v[k].x), h1 = (unsigned)sbin_of(v[k].y);
            unsigned h2 = (unsigned)sbin_of(v[k].z), h3 = (unsigned)sbin_of(v[k].w);
            c6 += (h0 <= b6) + (h1 <= b6) + (h2 <= b6) + (h3 <= b6);
            cA += (h0 <= bA) + (h1 <= bA) + (h2 <= bA) + (h3 <= bA);
        }
    }
    int ntail = n4 << 2;
    for (int i = ntail + gtid; i < n; i += T) {
        unsigned hb = (unsigned)sbin_of(score[i]);
        c6 += (hb <= b6);
        cA += (hb <= bA);
    }
    psum[tid] = (cA << 16) | c6;
    __syncthreads();
    for (int off = 1; off < 256; off <<= 1) {
        unsigned v = (tid >= off) ? psum[tid - off] : 0u;
        __syncthreads();
        psum[tid] += v;
        __syncthreads();
    }
    if (tid == 0) {
        unsigned tot = psum[255];
        sbase[0] = atomicAdd(&cnts[1], tot & 0xFFFFu);
        sbase[1] = atomicAdd(&cnts[0], tot >> 16);
    }
    __syncthreads();
    unsigned excl = (tid == 0) ? 0u : psum[tid - 1];
    unsigned pos6 = sbase[0] + (excl & 0xFFFFu);
    unsigned posA = sbase[1] + (excl >> 16);
    // phase 2: reload (L2-hot), decode winners (~6.5K total), write keys
    for (int idx0 = gtid; idx0 < n4; idx0 += T * 8) {
        float4 v[8]; int ok[8];
#pragma unroll
        for (int k = 0; k < 8; ++k) {
            int idx = idx0 + k * T;
            ok[k] = idx < n4;
            v[k] = ok[k] ? s4[idx] : make_float4(0.f, 0.f, 0.f, 0.f);
        }
#pragma unroll
        for (int k = 0; k < 8; ++k) if (ok[k]) {
            float sc[4] = {v[k].x, v[k].y, v[k].z, v[k].w};
            int ib = (idx0 + k * T) << 2;
#pragma unroll
            for (int c = 0; c < 4; ++c) {
                unsigned hb = (unsigned)sbin_of(sc[c]);
                if (hb <= b6) {
                    int i = ib + c;
                    float4 r = decode_box(anchor[i], loc[i], ih, iw);
                    bool valid = ((r.z - r.x) >= MINSZ) && ((r.w - r.y) >= MINSZ);
                    float ms = valid ? sc[c] : -__builtin_inff();
                    u64 key = ((u64)inv_key(ms) << 32) | (unsigned)i;
                    if (pos6 < CAP6) cand6[pos6] = key;
                    pos6++;
                    if (hb <= bA) {
                        if (posA < CAPA) candA[posA] = key;
                        posA++;
                    }
                }
            }
        }
    }
    for (int i = ntail + gtid; i < n; i += T) {
        float s = score[i];
        unsigned hb = (unsigned)sbin_of(s);
        if (hb <= b6) {
            float4 r = decode_box(anchor[i], loc[i], ih, iw);
            bool valid = ((r.z - r.x) >= MINSZ) && ((r.w - r.y) >= MINSZ);
            float ms = valid ? s : -__builtin_inff();
            u64 key = ((u64)inv_key(ms) << 32) | (unsigned)i;
            if (pos6 < CAP6) cand6[pos6] = key;
            pos6++;
            if (hb <= bA) {
                if (posA < CAPA) candA[posA] = key;
                posA++;
            }
        }
    }
}

struct SmFb {
    u64   lk[CAP6];                                // 64 KB
    float y1[NPOST], x1[NPOST], y2[NPOST], x2[NPOST], ar[NPOST];
};

// ---- 3: fused: counting-sort rank -> decode -> TRANSPOSED matrix -> (last) ballot scan ----
__global__ void __launch_bounds__(256) k_rankmat(
        const float4* __restrict__ loc, const float4* __restrict__ anchor,
        const int* __restrict__ ph, const int* __restrict__ pw, int n,
        const u64* __restrict__ candA, const u64* __restrict__ cand6,
        unsigned* __restrict__ cnts, u64* __restrict__ gmatT,
        unsigned* __restrict__ order6, float4* __restrict__ roi6,
        float* __restrict__ out) {
    __shared__ u64 skey[CAPA];          // 16 KB
    __shared__ unsigned shist[NBIN];    // 8 KB
    __shared__ unsigned sprefix[NBIN];  // 8 KB
    __shared__ float4 sroi[CA];         // 6 KB
    __shared__ float  sarea[CA];        // 1.5 KB
    __shared__ unsigned svalid[CA / 32];
    __shared__ unsigned swave[8];
    __shared__ unsigned sInvLo;
    __shared__ int sIsLast;
    __shared__ u64 skm[NG];
    __shared__ int snk, sflag;
    __shared__ SmFb fb;                 // fallback only
    int tid = threadIdx.x;
    unsigned cntA = cnts[0];
    bool mainValid = (cntA <= CAPA);
    unsigned MA = mainValid ? cntA : 0;
    float ih = (float)ph[0], iw = (float)pw[0];

    if (mainValid) {
        if (tid == 0) sInvLo = 0xFFFFFFFFu;
        for (int b = tid; b < NBIN; b += 256) shist[b] = 0;
        for (int r = tid; r < CA; r += 256) { sroi[r] = make_float4(0.f,0.f,0.f,0.f); sarea[r] = 0.f; }
        if (tid < CA / 32) svalid[tid] = 0;
        u64 kreg[8];
#pragma unroll
        for (int k = 0; k < 8; ++k) {
            unsigned i = tid + k * 256u;
            kreg[k] = (i < MA) ? candA[i] : ~0ULL;
        }
        unsigned mymin = 0xFFFFFFFFu;
#pragma unroll
        for (int k = 0; k < 8; ++k) {
            unsigned hi = (unsigned)(kreg[k] >> 32);
            mymin = mymin < hi ? mymin : hi;
        }
#pragma unroll
        for (int off = 32; off; off >>= 1) {
            unsigned o = (unsigned)__shfl_down((int)mymin, off, 64);
            mymin = mymin < o ? mymin : o;
        }
        if ((tid & 63) == 0) atomicMin(&sInvLo, mymin);
        __syncthreads();
        unsigned invLo = sInvLo;
#pragma unroll
        for (int k = 0; k < 8; ++k) {
            unsigned i = tid + k * 256u;
            if (i < MA) {
                unsigned d = ((unsigned)(kreg[k] >> 32) - invLo) >> 3;
                atomicAdd(&shist[d > 2047u ? 2047u : d], 1u);
            }
        }
        __syncthreads();
        {   // fast exclusive prefix into sprefix
            unsigned vals[8], s = 0;
#pragma unroll
            for (int j = 0; j < 8; ++j) { vals[j] = shist[tid * 8 + j]; s += vals[j]; }
            unsigned inc = s;
#pragma unroll
            for (int off = 1; off < 64; off <<= 1) {
                unsigned o = (unsigned)__shfl_up((int)inc, off, 64);
                if ((tid & 63) >= off) inc += o;
            }
            if ((tid & 63) == 63) swave[tid >> 6] = inc;
            __syncthreads();
            unsigned wbase = 0;
            for (int w = 0; w < (tid >> 6); ++w) wbase += swave[w];
            unsigned run = wbase + inc - s;
#pragma unroll
            for (int j = 0; j < 8; ++j) { sprefix[tid * 8 + j] = run; run += vals[j]; }
        }
        __syncthreads();
#pragma unroll
        for (int k = 0; k < 8; ++k) {
            unsigned i = tid + k * 256u;
            if (i < MA) {
                unsigned d = ((unsigned)(kreg[k] >> 32) - invLo) >> 3;
                d = d > 2047u ? 2047u : d;
                unsigned pos = atomicAdd(&sprefix[d], 1u);
                skey[pos] = kreg[k];
            }
        }
        __syncthreads();
#pragma unroll
        for (int k = 0; k < 8; ++k) {
            unsigned p = tid + k * 256u;
            if (p < MA) {
                u64 key = skey[p];
                unsigned d = ((unsigned)(key >> 32) - invLo) >> 3;
                d = d > 2047u ? 2047u : d;
                unsigned e = sprefix[d];
                unsigned s0 = e - shist[d];
                int rank = (int)s0;
                for (unsigned q = s0; q < e; ++q) rank += (skey[q] < key) ? 1 : 0;
                if (rank < CA) {
                    unsigned idx = (unsigned)key;
                    float4 b = decode_box(anchor[idx], loc[idx], ih, iw);
                    sroi[rank] = b;
                    sarea[rank] = (b.z - b.x) * (b.w - b.y);
                    if (((b.z - b.x) >= MINSZ) && ((b.w - b.y) >= MINSZ))
                        atomicOr(&svalid[rank >> 5], 1u << (rank & 31));
                }
            }
        }
        __syncthreads();
        // TRANSPOSED matrix slice: task -> (row-group gr, column jcol).
        // gmatT[gr*CA + jcol] bit c = "row (64*gr+c) suppresses column jcol" (row < col only)
        {
            int task = blockIdx.x * 256 + tid;
            int gr = task / CA;
            int jcol = task - gr * CA;
            int j0 = gr << 6;
            u64 bits = 0;
            if (j0 < jcol) {
                float4 b = sroi[jcol];
                float ab = sarea[jcol];
                int cmax = jcol - j0; cmax = cmax > 64 ? 64 : cmax;
                for (int c = 0; c < cmax; ++c) {
                    int row = j0 + c;
                    float4 r = sroi[row];
                    float yy1 = fmaxf(r.x, b.x);
                    float xx1 = fmaxf(r.y, b.y);
                    float yy2 = fminf(r.z, b.z);
                    float xx2 = fminf(r.w, b.w);
                    float inter = fmaxf(yy2 - yy1, 0.0f) * fmaxf(xx2 - xx1, 0.0f);
                    float iou = inter / (sarea[row] + ab - inter);  // ref op order
                    if (iou > NMS_T) bits |= (1ULL << c);
                }
            }
            gmatT[gr * CA + jcol] = bits;
        }
    }
    // release our writes, count blocks done; last block runs the scan
    __threadfence();
    __syncthreads();
    if (tid == 0) {
        unsigned d = atomicAdd(&cnts[2], 1u);
        sIsLast = (d == GRIDR - 1);
    }
    __syncthreads();
    if (!sIsLast) return;
    __threadfence();   // acquire: other blocks' gmatT writes now visible

    // ---- scan phase (this block only): ballot-based, no readlane ----
    unsigned cnt6 = cnts[1];
    int Ceff = (int)(cntA < (unsigned)CA ? cntA : (unsigned)CA);
    if (tid < 64 && mainValid) {
        // lane j: W[gq] = gmatT[g*CA + 64*gq + j] = rows(group g) suppressing col 64*gq+j
        u64 supfut[NG], W[NG], nxtW[NG], kmask[NG];
#pragma unroll
        for (int w = 0; w < NG; ++w) {
            supfut[w] = ~(((u64)svalid[2 * w + 1] << 32) | (u64)svalid[2 * w]);
            kmask[w] = 0ull;
        }
#pragma unroll
        for (int gq = 0; gq < NG; ++gq) W[gq] = gmatT[0 * CA + 64 * gq + tid];
        int nk = 0;
        bool done = false;
#pragma unroll
        for (int g = 0; g < NG; ++g) {
            if (g < NG - 1) {
#pragma unroll
                for (int gq = 0; gq < NG; ++gq) nxtW[gq] = gmatT[(g + 1) * CA + 64 * gq + tid];
            }
            int base = 64 * g;
            if (!done && base < Ceff) {
                u64 bound = (Ceff - base >= 64) ? ~0ull : ((1ull << (Ceff - base)) - 1ull);
                u64 live = ~supfut[g] & bound;
                u64 km = 0;
                while (live) {
                    int b = (int)__builtin_ctzll(live);
                    km |= 1ull << b;
                    ++nk;
                    if (nk == NPOST) { done = true; break; }
                    bool s = (W[g] >> b) & 1ull;          // my column suppressed by row b?
                    u64 supm = __ballot(s);               // uniform suppressed-mask
                    live &= ~(supm | (1ull << b));
                }
                kmask[g] = km;
                if (!done && g < NG - 1) {                // deferred cross-group fold
#pragma unroll
                    for (int gq = 0; gq < NG; ++gq) {
                        if (gq > g) {
                            bool any = (W[gq] & km) != 0ull;
                            supfut[gq] |= __ballot(any);
                        }
                    }
                }
            }
#pragma unroll
            for (int gq = 0; gq < NG; ++gq) W[gq] = nxtW[gq];
        }
        if (tid == 0) {
            snk = nk;
            sflag = (nk < NPOST && cnt6 > (unsigned)Ceff) ? 1 : 0;
#pragma unroll
            for (int g = 0; g < NG; ++g) skm[g] = kmask[g];
        }
    }
    if (tid == 0 && !mainValid) {
        snk = 0; sflag = 1;
#pragma unroll
        for (int g = 0; g < NG; ++g) skm[g] = 0ull;
    }
    __syncthreads();
    int nk = snk, flag = sflag;
    float4* out4 = (float4*)out;
    if (!flag) {
        int basepc[NG];
        {
            int run = 0;
#pragma unroll
            for (int g = 0; g < NG; ++g) { basepc[g] = run; run += __popcll(skm[g]); }
        }
        int wv = tid >> 6, j = tid & 63;
#pragma unroll
        for (int gg = 0; gg < 2; ++gg) {
            int g = wv + 4 * gg;
            if (g < NG) {
                u64 km = skm[g];
                if ((km >> j) & 1ull) {
                    int rank = basepc[g] + __popcll(km & ((1ull << j) - 1ull));
                    if (rank < NPOST) out4[rank] = sroi[64 * g + j];
                }
            }
        }
        for (int k = nk + tid; k < NPOST; k += 256) out4[k] = make_float4(0.f,0.f,0.f,0.f);
        return;
    }
    // ---------- exact fallback (gated; never taken on sane data) ----------
    unsigned M = cnt6 < (unsigned)CAP6 ? cnt6 : (unsigned)CAP6;
    for (unsigned i = tid; i < CAP6; i += 256) fb.lk[i] = (i < M) ? cand6[i] : ~0ULL;
    for (int r = tid; r < NPRE; r += 256) order6[r] = 0xFFFFFFFFu;
    __syncthreads();
    for (unsigned c = tid; c < M; c += 256) {
        u64 key = fb.lk[c];
        int rank = 0;
        for (unsigned j = 0; j < M; ++j) rank += (fb.lk[j] < key) ? 1 : 0;
        if (rank < NPRE) order6[rank] = (unsigned)key;
    }
    __syncthreads();
    for (int r = tid; r < NPRE; r += 256) {
        unsigned idx = order6[r];
        float4 b = make_float4(0.f, 0.f, 0.f, 0.f);
        if (idx < (unsigned)n) b = decode_box(anchor[idx], loc[idx], ih, iw);
        roi6[r] = b;
    }
    __syncthreads();
    if (tid < 64) {
        int lane = tid;
        int nk2 = 0;
        for (int i = 0; i < NPRE; i++) {
            float4 b = roi6[i];
            float hs = b.z - b.x, wd = b.w - b.y;
            if (!(hs >= MINSZ && wd >= MINSZ)) continue;
            float ab = hs * wd;
            bool sup = false;
            for (int base = 0; base < nk2 && !sup; base += 64) {
                int t = base + lane;
                bool s = false;
                if (t < nk2) {
                    float yy1 = fmaxf(b.x, fb.y1[t]);
                    float xx1 = fmaxf(b.y, fb.x1[t]);
                    float yy2 = fminf(b.z, fb.y2[t]);
                    float xx2 = fminf(b.w, fb.x2[t]);
                    float inter = fmaxf(yy2 - yy1, 0.0f) * fmaxf(xx2 - xx1, 0.0f);
                    float iou = inter / (fb.ar[t] + ab - inter);
                    s = iou > NMS_T;
                }
                sup = (__ballot(s) != 0ULL);
            }
            if (!sup) {
                if (lane == 0) {
                    fb.y1[nk2] = b.x; fb.x1[nk2] = b.y;
                    fb.y2[nk2] = b.z; fb.x2[nk2] = b.w; fb.ar[nk2] = ab;
                }
                nk2++;
                if (nk2 == NPOST) break;
            }
        }
        for (int k = lane; k < NPOST; k += 64) {
            float4 o = make_float4(0.f, 0.f, 0.f, 0.f);
            if (k < nk2) o = make_float4(fb.y1[k], fb.x1[k], fb.y2[k], fb.x2[k]);
            out4[k] = o;
        }
    }
}

extern "C" void kernel_launch(void* const* d_in, const int* in_sizes, int n_in,
                              void* d_out, int out_size, void* d_ws, size_t ws_size,
                              hipStream_t stream) {
    const float4* loc    = (const float4*)d_in[0];
    const float*  score  = (const float*)d_in[1];
    const float4* anchor = (const float4*)d_in[2];
    const int*    ph     = (const int*)d_in[3];
    const int*    pw     = (const int*)d_in[4];
    int n = in_sizes[1];

    char* ws = (char*)d_ws;
    u64*      cand6  = (u64*)(ws + OFF_CAND6);
    u64*      candA  = (u64*)(ws + OFF_CANDA);
    unsigned* order6 = (unsigned*)(ws + OFF_ORDER6);
    float4*   roi6   = (float4*)(ws + OFF_ROI6);
    u64*      gmatT  = (u64*)(ws + OFF_GMAT);
    unsigned* slots  = (unsigned*)(ws + OFF_SLOT);
    unsigned* cnts   = (unsigned*)(ws + OFF_CNT);
    float* out = (float*)d_out;

    k_hist    <<<dim3(NSLOT), dim3(256), 0, stream>>>(score, n, slots, cnts);
    k_compact <<<dim3(128),   dim3(256), 0, stream>>>(loc, score, anchor, ph, pw, n, slots,
                                                      candA, cand6, cnts);
    k_rankmat <<<dim3(GRIDR), dim3(256), 0, stream>>>(loc, anchor, ph, pw, n, candA, cand6,
                                                      cnts, gmatT, order6, roi6, out);
}